// Round 13
// baseline (547.076 us; speedup 1.0000x reference)
//
#include <hip/hip_runtime.h>

#define N_Q 8192
#define N_K 16384
#define C_DIM 256
#define BM 256
#define BN 256
#define BK 64
#define NGRAN 256   // 64-code granules
#define GRAN 64
// Rigorous worst-case |d_approx - d_np| <= 1.9e-4; flagging needs 2x = 3.8e-4.
#define MARGIN 4.5e-4f
#define PCAP 200000      // pair-list capacity (overflow -> fallback mode)
#define CCAP 4096        // chunk descriptor capacity
#define RQB 1024         // fallback-mode query window

typedef __attribute__((ext_vector_type(8))) short short8;
typedef __attribute__((ext_vector_type(4))) float f32x4;
typedef __attribute__((ext_vector_type(4))) unsigned short ushort4_t;
typedef unsigned long long u64;

__device__ inline unsigned short f2bf(float f) {  // RNE fp32->bf16 (finite)
  unsigned u = __float_as_uint(f);
  return (unsigned short)((u + 0x7fffu + ((u >> 16) & 1u)) >> 16);
}

__device__ inline void gl_lds16(const void* g, void* l) {
  __builtin_amdgcn_global_load_lds(
      (const __attribute__((address_space(1))) unsigned int*)g,
      (__attribute__((address_space(3))) unsigned int*)l, 16, 0, 0);
}

// ===========================================================================
// pre_x (R11-verified): LDS-tile transpose; exact R1 xsq order; init packed2.
// ===========================================================================
__global__ __launch_bounds__(256) void vq_pre_x(
    const float* __restrict__ hidden, float* __restrict__ xt,
    unsigned short* __restrict__ xb, float* __restrict__ xsq,
    u64* __restrict__ packed2) {
  __shared__ float xs[C_DIM][36];
  __shared__ float xsq_part[4][32];
  const int tile = blockIdx.x;       // 256 = 8 b x 32 hw-tiles
  const int b = tile >> 5;
  const int hw0 = (tile & 31) * 32;
  const int q0 = b * 1024 + hw0;
  const float* hb = hidden + (size_t)b * (C_DIM * 1024) + hw0;
  const int tid = threadIdx.x;

  for (int idx = tid; idx < C_DIM * 32; idx += 256) {
    int c = idx >> 5, q = idx & 31;
    xs[c][q] = hb[c * 1024 + q];     // coalesced over q
  }
  __syncthreads();

  if (tid < 128) {  // xsq partials, exact R1 c-ranges
    int q = tid & 31, part = tid >> 5, cb0 = part * 64;
    float s = 0.f;
    for (int c = 0; c < 64; ++c) { float v = xs[cb0 + c][q]; s = fmaf(v, v, s); }
    xsq_part[part][q] = s;
  }
  __syncthreads();
  if (tid < 32) {
    xsq[q0 + tid] = ((xsq_part[0][tid] + xsq_part[1][tid]) + xsq_part[2][tid]) +
                    xsq_part[3][tid];
    packed2[q0 + tid] = ~0ull;
  }

  {  // xt + xb row writes
    int q = tid >> 3, c0 = (tid & 7) * 32;
    float* xo = xt + (size_t)(q0 + q) * C_DIM + c0;
    unsigned short* bo = xb + (size_t)(q0 + q) * C_DIM + c0;
    for (int i = 0; i < 32; i += 4) {
      float4 v = {xs[c0 + i][q], xs[c0 + i + 1][q], xs[c0 + i + 2][q],
                  xs[c0 + i + 3][q]};
      *reinterpret_cast<float4*>(xo + i) = v;
      ushort4_t bv = {f2bf(v.x), f2bf(v.y), f2bf(v.z), f2bf(v.w)};
      *reinterpret_cast<ushort4_t*>(bo + i) = bv;
    }
  }
}

// ===========================================================================
// pre_e (R11-verified): coalesced staging; exact R1 esq chain; eb bf16.
// ===========================================================================
__global__ __launch_bounds__(256) void vq_pre_e(
    const float* __restrict__ cb, unsigned short* __restrict__ eb,
    float* __restrict__ esq) {
  __shared__ float es[64][257];
  const int k0 = blockIdx.x * 64;
  const int tid = threadIdx.x;

  for (int idx = tid; idx < 64 * 64; idx += 256) {
    int kk = idx >> 6, c4 = idx & 63;
    float4 v = reinterpret_cast<const float4*>(cb + (size_t)(k0 + kk) * C_DIM)[c4];
    es[kk][c4 * 4 + 0] = v.x; es[kk][c4 * 4 + 1] = v.y;
    es[kk][c4 * 4 + 2] = v.z; es[kk][c4 * 4 + 3] = v.w;
  }
  __syncthreads();

  if (tid < 64) {
    float s = 0.f;
    for (int c = 0; c < 256; ++c) { float v = es[tid][c]; s = fmaf(v, v, s); }
    esq[k0 + tid] = s;
  }

  {  // eb writes coalesced
    int r = tid >> 2, c0 = (tid & 3) * 64;
    unsigned short* bo = eb + (size_t)(k0 + r) * C_DIM + c0;
    for (int i = 0; i < 64; i += 4) {
      ushort4_t bv = {f2bf(es[r][c0 + i]), f2bf(es[r][c0 + i + 1]),
                      f2bf(es[r][c0 + i + 2]), f2bf(es[r][c0 + i + 3])};
      *reinterpret_cast<ushort4_t*>(bo + i) = bv;
    }
  }
}

// ===========================================================================
// Prefilter GEMM — exact R9/R11 config (verified 147us, conflicts=0).
// ===========================================================================
__global__ __launch_bounds__(512) void vq_gemm(
    const unsigned short* __restrict__ xb, const unsigned short* __restrict__ eb,
    const float* __restrict__ xsq, const float* __restrict__ esq,
    float* __restrict__ mins_t) {
  __shared__ __align__(16) unsigned short As[2][BM * BK];
  __shared__ __align__(16) unsigned short Bs[2][BN * BK];

  const int tid = threadIdx.x;
  const int wid = tid >> 6;
  const int lane = tid & 63;

  int bidx = blockIdx.x;
  int xcd = bidx & 7;
  int idx = bidx >> 3;
  int nb = xcd * 8 + (idx >> 5);
  int qb = idx & 31;
  const int q0 = qb * BM;
  const int n0 = nb * BN;

  const int wr = wid >> 2, wc = wid & 3;
  const int lrow = lane & 15;
  const int lkhi = lane >> 4;
  const int srow = lane >> 3;
  const int sseg = (lane & 7) ^ srow;

  auto stage = [&](int kt, int bf) {
#pragma unroll
    for (int i = 0; i < 4; ++i) {
      int r0 = (wid * 4 + i) * 8;
      gl_lds16(xb + (size_t)(q0 + r0 + srow) * C_DIM + kt * BK + sseg * 8,
               (void*)((char*)&As[bf][0] + (size_t)r0 * BK * 2));
      gl_lds16(eb + (size_t)(n0 + r0 + srow) * C_DIM + kt * BK + sseg * 8,
               (void*)((char*)&Bs[bf][0] + (size_t)r0 * BK * 2));
    }
  };

  f32x4 acc[8][4];
#pragma unroll
  for (int i = 0; i < 8; ++i)
#pragma unroll
    for (int j = 0; j < 4; ++j) acc[i][j] = (f32x4){0.f, 0.f, 0.f, 0.f};

  stage(0, 0);
  asm volatile("s_waitcnt vmcnt(0)" ::: "memory");
  __syncthreads();

  const int r7 = lrow & 7;
  for (int kt = 0; kt < C_DIM / BK; ++kt) {
    int bf = kt & 1;
    if (kt + 1 < C_DIM / BK) stage(kt + 1, bf ^ 1);
#pragma unroll
    for (int kk = 0; kk < 2; ++kk) {
      const int segA = ((kk * 4 + lkhi) ^ r7) * 8;
      short8 a[8], b[4];
#pragma unroll
      for (int mi = 0; mi < 8; ++mi)
        a[mi] = *(const short8*)((const char*)&As[bf][0] +
                 (size_t)((wr * 128 + mi * 16 + lrow) * BK + segA) * 2);
#pragma unroll
      for (int ni = 0; ni < 4; ++ni)
        b[ni] = *(const short8*)((const char*)&Bs[bf][0] +
                 (size_t)((wc * 64 + ni * 16 + lrow) * BK + segA) * 2);
#pragma unroll
      for (int mi = 0; mi < 8; ++mi)
#pragma unroll
        for (int ni = 0; ni < 4; ++ni)
          acc[mi][ni] = __builtin_amdgcn_mfma_f32_16x16x32_bf16(
              a[mi], b[ni], acc[mi][ni], 0, 0, 0);
    }
    asm volatile("s_waitcnt vmcnt(0)" ::: "memory");
    __syncthreads();
  }

  float eqv[4];
#pragma unroll
  for (int ni = 0; ni < 4; ++ni) eqv[ni] = esq[n0 + wc * 64 + ni * 16 + lrow];
  const int g = nb * 4 + wc;
#pragma unroll
  for (int mi = 0; mi < 8; ++mi) {
#pragma unroll
    for (int j = 0; j < 4; ++j) {
      int row = q0 + wr * 128 + mi * 16 + lkhi * 4 + j;
      float xq = xsq[row];
      u64 bst = ~0ull;
#pragma unroll
      for (int ni = 0; ni < 4; ++ni) {
        float d = (xq + eqv[ni]) - 2.0f * acc[mi][ni][j];
        int k = n0 + wc * 64 + ni * 16 + lrow;
        u64 p = ((u64)__float_as_uint(d) << 32) | (unsigned)k;
        if (p < bst) bst = p;
      }
#pragma unroll
      for (int m = 1; m <= 8; m <<= 1) {
        u64 o = __shfl_xor(bst, m);
        if (o < bst) bst = o;
      }
      if (lrow == 0)
        mins_t[(size_t)g * N_Q + row] = __uint_as_float((unsigned)(bst >> 32));
    }
  }
}

// ===========================================================================
// thr[q] = min_g mins_t[g][q] + MARGIN; also zero counters.
// ===========================================================================
__global__ __launch_bounds__(256) void vq_thr(const float* __restrict__ mins_t,
                                              float* __restrict__ thr,
                                              int* __restrict__ gcnt,
                                              int* __restrict__ gcursor,
                                              int* __restrict__ meta) {
  int q = blockIdx.x * 256 + threadIdx.x;
  float m = 3.4e38f;
  for (int g = 0; g < NGRAN; ++g) m = fminf(m, mins_t[(size_t)g * N_Q + q]);
  thr[q] = m + MARGIN;
  if (q < NGRAN) { gcnt[q] = 0; gcursor[q] = 0; }
  if (q < 4) meta[q] = 0;
}

// ===========================================================================
// hist: per-granule flag counts. 32 blocks x 256 queries; per-g coalesced
// row reads; LDS histogram then 256 global adds per block.
// ===========================================================================
__global__ __launch_bounds__(256) void vq_hist(const float* __restrict__ mins_t,
                                               const float* __restrict__ thr,
                                               int* __restrict__ gcnt) {
  __shared__ int h[NGRAN];
  const int tid = threadIdx.x;
  const int q = blockIdx.x * 256 + tid;
  h[tid] = 0;
  __syncthreads();
  const float t = thr[q];
  for (int g = 0; g < NGRAN; ++g) {
    if (mins_t[(size_t)g * N_Q + q] <= t) atomicAdd(&h[g], 1);
  }
  __syncthreads();
  if (h[tid]) atomicAdd(&gcnt[tid], h[tid]);
}

// ===========================================================================
// chunks: 1 block. LDS prefix of gcnt -> goff; chunk descriptors (<=64 pairs,
// single granule each, built in parallel via chunk-count prefix). Overflow
// (P > PCAP) -> mode=1 (fallback). meta = {P, C, mode}.
// ===========================================================================
__global__ __launch_bounds__(256) void vq_chunks(const int* __restrict__ gcnt,
                                                 int* __restrict__ goff,
                                                 unsigned* __restrict__ chunks,
                                                 int* __restrict__ meta) {
  __shared__ int cnt[NGRAN], off[NGRAN + 1], nch[NGRAN], choff[NGRAN + 1];
  const int tid = threadIdx.x;
  cnt[tid] = gcnt[tid];
  __syncthreads();
  if (tid == 0) {
    int s = 0;
    for (int g = 0; g < NGRAN; ++g) { off[g] = s; s += cnt[g]; }
    off[NGRAN] = s;
  }
  __syncthreads();
  nch[tid] = (cnt[tid] + 63) >> 6;
  __syncthreads();
  if (tid == 0) {
    int s = 0;
    for (int g = 0; g < NGRAN; ++g) { choff[g] = s; s += nch[g]; }
    choff[NGRAN] = s;
  }
  __syncthreads();
  const int P = off[NGRAN];
  const int C = choff[NGRAN];
  goff[tid] = off[tid];
  if (tid == 0) {
    goff[NGRAN] = P;
    meta[0] = P;
    meta[1] = (P > PCAP || C > CCAP) ? 2048 : C;
    meta[2] = (P > PCAP || C > CCAP) ? 1 : 0;
  }
  if (!(P > PCAP || C > CCAP)) {
    for (int c = 0; c < nch[tid]; ++c)
      chunks[choff[tid] + c] = ((unsigned)tid << 20) | (unsigned)(c * 64);
  }
}

// ===========================================================================
// scatter: write flagged q into granule-sorted plist (guarded by PCAP).
// Order within granule is atomic-nondeterministic; the SET is deterministic
// and the final atomicMin merge is order-invariant.
// ===========================================================================
__global__ __launch_bounds__(256) void vq_scatter(
    const float* __restrict__ mins_t, const float* __restrict__ thr,
    const int* __restrict__ goff, int* __restrict__ gcursor,
    int* __restrict__ plist) {
  const int q = blockIdx.x * 256 + threadIdx.x;
  const float t = thr[q];
  for (int g = 0; g < NGRAN; ++g) {
    if (mins_t[(size_t)g * N_Q + q] <= t) {
      int pos = atomicAdd(&gcursor[g], 1);
      int idx = goff[g] + pos;
      if (idx < PCAP) plist[idx] = q;
    }
  }
}

// ===========================================================================
// rescore_c: grid-stride over uniform chunks (<=64 pairs, one granule).
// Stage granule codes once (cL[64][257], (l+c)%32 -> 2-way free), 4 waves x
// 8-query-ILP EXACT R1 fmaf chains, u64 atomicMin -> packed2. mode==1
// fallback = R12-style (granule, window) scan (correct, slower; never
// expected to trigger).
// ===========================================================================
__global__ __launch_bounds__(256) void vq_rescore_c(
    const float* __restrict__ xt, const float* __restrict__ cb,
    const float* __restrict__ xsq, const float* __restrict__ esq,
    const float* __restrict__ mins_t, const float* __restrict__ thr,
    const int* __restrict__ goff, const int* __restrict__ gcnt,
    const int* __restrict__ plist, const unsigned* __restrict__ chunks,
    const int* __restrict__ meta, u64* __restrict__ packed2) {
  __shared__ float cL[GRAN][C_DIM + 1];  // 64.25KB
  __shared__ int lbuf[RQB];              // fallback worklist (4KB)
  __shared__ int lcnt;
  const int tid = threadIdx.x;
  const int w = tid >> 6;
  const int l = tid & 63;
  const int mode = meta[2];
  const int C = meta[1];

  if (mode == 0) {
    for (int ci = blockIdx.x; ci < C; ci += gridDim.x) {
      unsigned desc = chunks[ci];
      const int g = desc >> 20;
      const int s0 = desc & 0xFFFFF;
      const int n = min(64, gcnt[g] - s0);
      __syncthreads();  // protect cL from previous chunk's readers
      {  // stage granule codes
        const int kk = tid >> 2;
        const int seg = tid & 3;
        const float4* row = (const float4*)(cb + (size_t)(g * GRAN + kk) * C_DIM);
#pragma unroll
        for (int i = 0; i < 16; ++i) {
          int c4 = seg * 16 + i;
          float4 v = row[c4];
          cL[kk][c4 * 4 + 0] = v.x;
          cL[kk][c4 * 4 + 1] = v.y;
          cL[kk][c4 * 4 + 2] = v.z;
          cL[kk][c4 * 4 + 3] = v.w;
        }
      }
      __syncthreads();
      const int k = g * GRAN + l;
      const float eq = esq[k];
      const float* cr = &cL[l][0];
      const int base = goff[g] + s0;
      for (int i0 = w * 8; i0 < n; i0 += 32) {
        int qi[8];
#pragma unroll
        for (int j = 0; j < 8; ++j) {
          int ii = i0 + j;
          qi[j] = plist[base + (ii < n ? ii : n - 1)];
        }
        const float4* xp[8];
#pragma unroll
        for (int j = 0; j < 8; ++j)
          xp[j] = (const float4*)(xt + (size_t)qi[j] * C_DIM);
        float a[8];
#pragma unroll
        for (int j = 0; j < 8; ++j) a[j] = 0.f;
#pragma unroll 2
        for (int c4 = 0; c4 < 64; ++c4) {
          float e0 = cr[c4 * 4 + 0];
          float e1 = cr[c4 * 4 + 1];
          float e2 = cr[c4 * 4 + 2];
          float e3 = cr[c4 * 4 + 3];
#pragma unroll
          for (int j = 0; j < 8; ++j) {
            float4 v = xp[j][c4];
            float t = a[j];
            t = fmaf(v.x, e0, t);
            t = fmaf(v.y, e1, t);
            t = fmaf(v.z, e2, t);
            t = fmaf(v.w, e3, t);
            a[j] = t;
          }
        }
#pragma unroll
        for (int j = 0; j < 8; ++j) {
          float d = (xsq[qi[j]] + eq) - 2.0f * a[j];
          u64 p = ((u64)__float_as_uint(d) << 32) | (unsigned)k;
#pragma unroll
          for (int s = 1; s <= 32; s <<= 1) {
            u64 o = __shfl_xor(p, s);
            if (o < p) p = o;
          }
          if (l == 0) atomicMin(&packed2[qi[j]], p);
        }
      }
    }
    return;
  }

  // --------- fallback mode (P > PCAP): R12-style, correct, slow ---------
  if (blockIdx.x >= 2048) return;
  const int g = blockIdx.x >> 3;
  const int qbase = (blockIdx.x & 7) * RQB;
  if (tid == 0) lcnt = 0;
  __syncthreads();
  const float* mrow = mins_t + (size_t)g * N_Q + qbase;
  for (int c = tid; c < RQB; c += 256) {
    if (mrow[c] <= thr[qbase + c]) {
      int pos = atomicAdd(&lcnt, 1);
      lbuf[pos] = qbase + c;
    }
  }
  __syncthreads();
  const int n = lcnt;
  if (n == 0) return;
  {
    const int kk = tid >> 2;
    const int seg = tid & 3;
    const float4* row = (const float4*)(cb + (size_t)(g * GRAN + kk) * C_DIM);
#pragma unroll
    for (int i = 0; i < 16; ++i) {
      int c4 = seg * 16 + i;
      float4 v = row[c4];
      cL[kk][c4 * 4 + 0] = v.x;
      cL[kk][c4 * 4 + 1] = v.y;
      cL[kk][c4 * 4 + 2] = v.z;
      cL[kk][c4 * 4 + 3] = v.w;
    }
  }
  __syncthreads();
  const int k = g * GRAN + l;
  const float eq = esq[k];
  const float* cr = &cL[l][0];
  for (int i0 = w * 8; i0 < n; i0 += 32) {
    int qi[8];
#pragma unroll
    for (int j = 0; j < 8; ++j) {
      int ii = i0 + j;
      qi[j] = lbuf[ii < n ? ii : n - 1];
    }
    const float4* xp[8];
#pragma unroll
    for (int j = 0; j < 8; ++j)
      xp[j] = (const float4*)(xt + (size_t)qi[j] * C_DIM);
    float a[8];
#pragma unroll
    for (int j = 0; j < 8; ++j) a[j] = 0.f;
#pragma unroll 2
    for (int c4 = 0; c4 < 64; ++c4) {
      float e0 = cr[c4 * 4 + 0];
      float e1 = cr[c4 * 4 + 1];
      float e2 = cr[c4 * 4 + 2];
      float e3 = cr[c4 * 4 + 3];
#pragma unroll
      for (int j = 0; j < 8; ++j) {
        float4 v = xp[j][c4];
        float t = a[j];
        t = fmaf(v.x, e0, t);
        t = fmaf(v.y, e1, t);
        t = fmaf(v.z, e2, t);
        t = fmaf(v.w, e3, t);
        a[j] = t;
      }
    }
#pragma unroll
    for (int j = 0; j < 8; ++j) {
      float d = (xsq[qi[j]] + eq) - 2.0f * a[j];
      u64 p = ((u64)__float_as_uint(d) << 32) | (unsigned)k;
#pragma unroll
      for (int s = 1; s <= 32; s <<= 1) {
        u64 o = __shfl_xor(p, s);
        if (o < p) p = o;
      }
      if (l == 0) atomicMin(&packed2[qi[j]], p);
    }
  }
}

__global__ __launch_bounds__(256) void vq_out(const u64* __restrict__ packed2,
                                              int* __restrict__ out) {
  int n = blockIdx.x * 256 + threadIdx.x;
  if (n < N_Q) out[n] = (int)(unsigned)(packed2[n] & 0xffffffffull);
}

// ===========================================================================
// Fallback (R1, known-pass) if ws too small.
// ===========================================================================
#define TQ 64
#define TK 64
#define R1_NCH 8
#define R1_KCHUNK (N_K / R1_NCH)

__global__ __launch_bounds__(256) void r1_esq(const float* __restrict__ cb,
                                              float* __restrict__ esq) {
  int k = blockIdx.x * blockDim.x + threadIdx.x;
  if (k >= N_K) return;
  const float4* row = reinterpret_cast<const float4*>(cb + (size_t)k * C_DIM);
  float s = 0.f;
#pragma unroll 8
  for (int c4 = 0; c4 < C_DIM / 4; ++c4) {
    float4 v = row[c4];
    s = fmaf(v.x, v.x, s); s = fmaf(v.y, v.y, s);
    s = fmaf(v.z, v.z, s); s = fmaf(v.w, v.w, s);
  }
  esq[k] = s;
}

__global__ __launch_bounds__(256) void r1_main(
    const float* __restrict__ hidden, const float* __restrict__ cb,
    const float* __restrict__ esq, float* __restrict__ ws_d,
    int* __restrict__ ws_k) {
  __shared__ __align__(16) float xs[C_DIM][TQ + 4];
  __shared__ __align__(16) float es[TK][C_DIM + 4];
  __shared__ float xsq_part[4][TQ];
  __shared__ float xsq[TQ];
  __shared__ float red_d[16][TQ];
  __shared__ int red_k[16][TQ];
  const int tid = threadIdx.x;
  const int q0 = blockIdx.x * TQ;
  const int b = q0 >> 10;
  const int hw0 = q0 & 1023;
  const float* hb = hidden + (size_t)b * (C_DIM * 1024) + hw0;
  for (int idx = tid; idx < C_DIM * TQ; idx += 256) {
    int c = idx >> 6, q = idx & 63;
    xs[c][q] = hb[c * 1024 + q];
  }
  __syncthreads();
  {
    int q = tid & 63, part = tid >> 6, cbase = part * 64;
    float s = 0.f;
    for (int c = 0; c < 64; ++c) { float v = xs[cbase + c][q]; s = fmaf(v, v, s); }
    xsq_part[part][q] = s;
  }
  __syncthreads();
  if (tid < TQ)
    xsq[tid] = ((xsq_part[0][tid] + xsq_part[1][tid]) + xsq_part[2][tid]) + xsq_part[3][tid];
  __syncthreads();
  const int qt = tid & 15, kt = tid >> 4;
  float xsq_r[4];
#pragma unroll
  for (int i = 0; i < 4; ++i) xsq_r[i] = xsq[qt * 4 + i];
  float bd[4]; int bk[4];
#pragma unroll
  for (int i = 0; i < 4; ++i) { bd[i] = 3.4e38f; bk[i] = 0x7fffffff; }
  const int kbegin = blockIdx.y * R1_KCHUNK;
  for (int kt0 = kbegin; kt0 < kbegin + R1_KCHUNK; kt0 += TK) {
    __syncthreads();
    for (int idx = tid; idx < TK * (C_DIM / 4); idx += 256) {
      int kk = idx >> 6, c4 = idx & 63;
      float4 v = reinterpret_cast<const float4*>(cb + (size_t)(kt0 + kk) * C_DIM)[c4];
      es[kk][c4 * 4 + 0] = v.x; es[kk][c4 * 4 + 1] = v.y;
      es[kk][c4 * 4 + 2] = v.z; es[kk][c4 * 4 + 3] = v.w;
    }
    __syncthreads();
    float acc[4][4];
#pragma unroll
    for (int i = 0; i < 4; ++i)
#pragma unroll
      for (int j = 0; j < 4; ++j) acc[i][j] = 0.f;
    for (int c4 = 0; c4 < C_DIM; c4 += 4) {
      float4 xv0 = *reinterpret_cast<const float4*>(&xs[c4 + 0][qt * 4]);
      float4 xv1 = *reinterpret_cast<const float4*>(&xs[c4 + 1][qt * 4]);
      float4 xv2 = *reinterpret_cast<const float4*>(&xs[c4 + 2][qt * 4]);
      float4 xv3 = *reinterpret_cast<const float4*>(&xs[c4 + 3][qt * 4]);
      float xq0[4] = {xv0.x, xv0.y, xv0.z, xv0.w};
      float xq1[4] = {xv1.x, xv1.y, xv1.z, xv1.w};
      float xq2[4] = {xv2.x, xv2.y, xv2.z, xv2.w};
      float xq3[4] = {xv3.x, xv3.y, xv3.z, xv3.w};
      float4 ev[4];
#pragma unroll
      for (int j = 0; j < 4; ++j)
        ev[j] = *reinterpret_cast<const float4*>(&es[kt * 4 + j][c4]);
#pragma unroll
      for (int i = 0; i < 4; ++i) {
#pragma unroll
        for (int j = 0; j < 4; ++j) {
          float a = acc[i][j];
          a = fmaf(xq0[i], ev[j].x, a);
          a = fmaf(xq1[i], ev[j].y, a);
          a = fmaf(xq2[i], ev[j].z, a);
          a = fmaf(xq3[i], ev[j].w, a);
          acc[i][j] = a;
        }
      }
    }
#pragma unroll
    for (int j = 0; j < 4; ++j) {
      int k = kt0 + kt * 4 + j;
      float eq = esq[k];
#pragma unroll
      for (int i = 0; i < 4; ++i) {
        float t1 = xsq_r[i] + eq;
        float d = t1 - 2.0f * acc[i][j];
        if (d < bd[i]) { bd[i] = d; bk[i] = k; }
      }
    }
  }
#pragma unroll
  for (int i = 0; i < 4; ++i) {
    red_d[kt][qt * 4 + i] = bd[i];
    red_k[kt][qt * 4 + i] = bk[i];
  }
  __syncthreads();
  if (tid < TQ) {
    float d = red_d[0][tid]; int kb = red_k[0][tid];
    for (int t = 1; t < 16; ++t) {
      float dn = red_d[t][tid]; int kn = red_k[t][tid];
      if (dn < d || (dn == d && kn < kb)) { d = dn; kb = kn; }
    }
    int q = q0 + tid;
    ws_d[(size_t)q * R1_NCH + blockIdx.y] = d;
    ws_k[(size_t)q * R1_NCH + blockIdx.y] = kb;
  }
}

__global__ __launch_bounds__(256) void r1_final(
    const float* __restrict__ ws_d, const int* __restrict__ ws_k,
    int* __restrict__ out) {
  int n = blockIdx.x * blockDim.x + threadIdx.x;
  if (n >= N_Q) return;
  const float* dp = ws_d + (size_t)n * R1_NCH;
  const int* kp = ws_k + (size_t)n * R1_NCH;
  float d = dp[0]; int kb = kp[0];
#pragma unroll
  for (int j = 1; j < R1_NCH; ++j) {
    float dn = dp[j]; int kn = kp[j];
    if (dn < d || (dn == d && kn < kb)) { d = dn; kb = kn; }
  }
  out[n] = kb;
}

extern "C" void kernel_launch(void* const* d_in, const int* in_sizes, int n_in,
                              void* d_out, int out_size, void* d_ws,
                              size_t ws_size, hipStream_t stream) {
  const float* hidden = (const float*)d_in[0];
  const float* cb = (const float*)d_in[1];
  int* out = (int*)d_out;

  const size_t MB = 1024 * 1024;
  const size_t KB = 1024;
  const size_t NEED = 29 * MB;  // proven available (R3/R5-R12 passed)

  if (ws_size >= NEED) {
    char* w = (char*)d_ws;
    unsigned short* xb = (unsigned short*)(w);                 // 4MB
    unsigned short* eb = (unsigned short*)(w + 4 * MB);        // 8MB
    float* xt = (float*)(w + 12 * MB);                         // 8MB
    float* mins_t = (float*)(w + 20 * MB);                     // 8MB [g][q]
    char* s = w + 28 * MB;                                     // 1MB small pool
    float* xsq = (float*)(s);                                  // 32KB
    float* thr = (float*)(s + 32 * KB);                        // 32KB
    float* esq = (float*)(s + 64 * KB);                        // 64KB
    u64* packed2 = (u64*)(s + 128 * KB);                       // 64KB
    int* gcnt = (int*)(s + 192 * KB);                          // 1KB
    int* gcursor = (int*)(s + 193 * KB);                       // 1KB
    int* goff = (int*)(s + 194 * KB);                          // 2KB
    int* meta = (int*)(s + 196 * KB);                          // 1KB
    unsigned* chunks = (unsigned*)(s + 197 * KB);              // 16KB
    int* plist = (int*)(s + 213 * KB);                         // ~800KB (PCAP)

    vq_pre_x<<<dim3(256), dim3(256), 0, stream>>>(hidden, xt, xb, xsq, packed2);
    vq_pre_e<<<dim3(N_K / 64), dim3(256), 0, stream>>>(cb, eb, esq);
    vq_gemm<<<dim3((N_Q / BM) * (N_K / BN)), dim3(512), 0, stream>>>(
        xb, eb, xsq, esq, mins_t);
    vq_thr<<<dim3(N_Q / 256), dim3(256), 0, stream>>>(mins_t, thr, gcnt,
                                                      gcursor, meta);
    vq_hist<<<dim3(N_Q / 256), dim3(256), 0, stream>>>(mins_t, thr, gcnt);
    vq_chunks<<<dim3(1), dim3(256), 0, stream>>>(gcnt, goff, chunks, meta);
    vq_scatter<<<dim3(N_Q / 256), dim3(256), 0, stream>>>(mins_t, thr, goff,
                                                          gcursor, plist);
    vq_rescore_c<<<dim3(4096), dim3(256), 0, stream>>>(
        xt, cb, xsq, esq, mins_t, thr, goff, gcnt, plist, chunks, meta,
        packed2);
    vq_out<<<dim3(N_Q / 256), dim3(256), 0, stream>>>(packed2, out);
  } else {
    float* esq_f = (float*)d_ws;
    float* ws_d = (float*)((char*)d_ws + 65536);
    int* ws_k = (int*)((char*)d_ws + 65536 + N_Q * R1_NCH * 4);
    r1_esq<<<dim3(N_K / 256), dim3(256), 0, stream>>>(cb, esq_f);
    r1_main<<<dim3(N_Q / TQ, R1_NCH), dim3(256), 0, stream>>>(hidden, cb, esq_f, ws_d, ws_k);
    r1_final<<<dim3(N_Q / 256), dim3(256), 0, stream>>>(ws_d, ws_k, out);
  }
}

// Round 14
// 356.880 us; speedup vs baseline: 1.5329x; 1.5329x over previous
//
#include <hip/hip_runtime.h>

#define N_Q 8192
#define N_K 16384
#define C_DIM 256
#define BM 256
#define BN 256
#define BK 64
#define NGRAN 256   // 64-code granules
#define GRAN 64
// Rigorous worst-case |d_approx - d_np| <= 1.9e-4; flagging needs 2x = 3.8e-4.
#define MARGIN 4.5e-4f
#define PCAP 200000      // pair-list capacity (overflow -> fallback mode)
#define CCAP 4096        // chunk descriptor capacity
#define RQB 1024         // fallback-mode / scatter slice size

typedef __attribute__((ext_vector_type(8))) short short8;
typedef __attribute__((ext_vector_type(4))) float f32x4;
typedef __attribute__((ext_vector_type(4))) unsigned short ushort4_t;
typedef unsigned long long u64;

__device__ inline unsigned short f2bf(float f) {  // RNE fp32->bf16 (finite)
  unsigned u = __float_as_uint(f);
  return (unsigned short)((u + 0x7fffu + ((u >> 16) & 1u)) >> 16);
}

__device__ inline void gl_lds16(const void* g, void* l) {
  __builtin_amdgcn_global_load_lds(
      (const __attribute__((address_space(1))) unsigned int*)g,
      (__attribute__((address_space(3))) unsigned int*)l, 16, 0, 0);
}

// ===========================================================================
// pre_x (R11-verified): LDS-tile transpose; exact R1 xsq order; init packed2.
// ===========================================================================
__global__ __launch_bounds__(256) void vq_pre_x(
    const float* __restrict__ hidden, float* __restrict__ xt,
    unsigned short* __restrict__ xb, float* __restrict__ xsq,
    u64* __restrict__ packed2) {
  __shared__ float xs[C_DIM][36];
  __shared__ float xsq_part[4][32];
  const int tile = blockIdx.x;       // 256 = 8 b x 32 hw-tiles
  const int b = tile >> 5;
  const int hw0 = (tile & 31) * 32;
  const int q0 = b * 1024 + hw0;
  const float* hb = hidden + (size_t)b * (C_DIM * 1024) + hw0;
  const int tid = threadIdx.x;

  for (int idx = tid; idx < C_DIM * 32; idx += 256) {
    int c = idx >> 5, q = idx & 31;
    xs[c][q] = hb[c * 1024 + q];     // coalesced over q
  }
  __syncthreads();

  if (tid < 128) {  // xsq partials, exact R1 c-ranges
    int q = tid & 31, part = tid >> 5, cb0 = part * 64;
    float s = 0.f;
    for (int c = 0; c < 64; ++c) { float v = xs[cb0 + c][q]; s = fmaf(v, v, s); }
    xsq_part[part][q] = s;
  }
  __syncthreads();
  if (tid < 32) {
    xsq[q0 + tid] = ((xsq_part[0][tid] + xsq_part[1][tid]) + xsq_part[2][tid]) +
                    xsq_part[3][tid];
    packed2[q0 + tid] = ~0ull;
  }

  {  // xt + xb row writes
    int q = tid >> 3, c0 = (tid & 7) * 32;
    float* xo = xt + (size_t)(q0 + q) * C_DIM + c0;
    unsigned short* bo = xb + (size_t)(q0 + q) * C_DIM + c0;
    for (int i = 0; i < 32; i += 4) {
      float4 v = {xs[c0 + i][q], xs[c0 + i + 1][q], xs[c0 + i + 2][q],
                  xs[c0 + i + 3][q]};
      *reinterpret_cast<float4*>(xo + i) = v;
      ushort4_t bv = {f2bf(v.x), f2bf(v.y), f2bf(v.z), f2bf(v.w)};
      *reinterpret_cast<ushort4_t*>(bo + i) = bv;
    }
  }
}

// ===========================================================================
// pre_e (R11-verified): coalesced staging; exact R1 esq chain; eb bf16.
// ===========================================================================
__global__ __launch_bounds__(256) void vq_pre_e(
    const float* __restrict__ cb, unsigned short* __restrict__ eb,
    float* __restrict__ esq) {
  __shared__ float es[64][257];
  const int k0 = blockIdx.x * 64;
  const int tid = threadIdx.x;

  for (int idx = tid; idx < 64 * 64; idx += 256) {
    int kk = idx >> 6, c4 = idx & 63;
    float4 v = reinterpret_cast<const float4*>(cb + (size_t)(k0 + kk) * C_DIM)[c4];
    es[kk][c4 * 4 + 0] = v.x; es[kk][c4 * 4 + 1] = v.y;
    es[kk][c4 * 4 + 2] = v.z; es[kk][c4 * 4 + 3] = v.w;
  }
  __syncthreads();

  if (tid < 64) {
    float s = 0.f;
    for (int c = 0; c < 256; ++c) { float v = es[tid][c]; s = fmaf(v, v, s); }
    esq[k0 + tid] = s;
  }

  {  // eb writes coalesced
    int r = tid >> 2, c0 = (tid & 3) * 64;
    unsigned short* bo = eb + (size_t)(k0 + r) * C_DIM + c0;
    for (int i = 0; i < 64; i += 4) {
      ushort4_t bv = {f2bf(es[r][c0 + i]), f2bf(es[r][c0 + i + 1]),
                      f2bf(es[r][c0 + i + 2]), f2bf(es[r][c0 + i + 3])};
      *reinterpret_cast<ushort4_t*>(bo + i) = bv;
    }
  }
}

// ===========================================================================
// Prefilter GEMM — exact R9/R11 config (verified 147us, conflicts=0).
// ===========================================================================
__global__ __launch_bounds__(512) void vq_gemm(
    const unsigned short* __restrict__ xb, const unsigned short* __restrict__ eb,
    const float* __restrict__ xsq, const float* __restrict__ esq,
    float* __restrict__ mins_t) {
  __shared__ __align__(16) unsigned short As[2][BM * BK];
  __shared__ __align__(16) unsigned short Bs[2][BN * BK];

  const int tid = threadIdx.x;
  const int wid = tid >> 6;
  const int lane = tid & 63;

  int bidx = blockIdx.x;
  int xcd = bidx & 7;
  int idx = bidx >> 3;
  int nb = xcd * 8 + (idx >> 5);
  int qb = idx & 31;
  const int q0 = qb * BM;
  const int n0 = nb * BN;

  const int wr = wid >> 2, wc = wid & 3;
  const int lrow = lane & 15;
  const int lkhi = lane >> 4;
  const int srow = lane >> 3;
  const int sseg = (lane & 7) ^ srow;

  auto stage = [&](int kt, int bf) {
#pragma unroll
    for (int i = 0; i < 4; ++i) {
      int r0 = (wid * 4 + i) * 8;
      gl_lds16(xb + (size_t)(q0 + r0 + srow) * C_DIM + kt * BK + sseg * 8,
               (void*)((char*)&As[bf][0] + (size_t)r0 * BK * 2));
      gl_lds16(eb + (size_t)(n0 + r0 + srow) * C_DIM + kt * BK + sseg * 8,
               (void*)((char*)&Bs[bf][0] + (size_t)r0 * BK * 2));
    }
  };

  f32x4 acc[8][4];
#pragma unroll
  for (int i = 0; i < 8; ++i)
#pragma unroll
    for (int j = 0; j < 4; ++j) acc[i][j] = (f32x4){0.f, 0.f, 0.f, 0.f};

  stage(0, 0);
  asm volatile("s_waitcnt vmcnt(0)" ::: "memory");
  __syncthreads();

  const int r7 = lrow & 7;
  for (int kt = 0; kt < C_DIM / BK; ++kt) {
    int bf = kt & 1;
    if (kt + 1 < C_DIM / BK) stage(kt + 1, bf ^ 1);
#pragma unroll
    for (int kk = 0; kk < 2; ++kk) {
      const int segA = ((kk * 4 + lkhi) ^ r7) * 8;
      short8 a[8], b[4];
#pragma unroll
      for (int mi = 0; mi < 8; ++mi)
        a[mi] = *(const short8*)((const char*)&As[bf][0] +
                 (size_t)((wr * 128 + mi * 16 + lrow) * BK + segA) * 2);
#pragma unroll
      for (int ni = 0; ni < 4; ++ni)
        b[ni] = *(const short8*)((const char*)&Bs[bf][0] +
                 (size_t)((wc * 64 + ni * 16 + lrow) * BK + segA) * 2);
#pragma unroll
      for (int mi = 0; mi < 8; ++mi)
#pragma unroll
        for (int ni = 0; ni < 4; ++ni)
          acc[mi][ni] = __builtin_amdgcn_mfma_f32_16x16x32_bf16(
              a[mi], b[ni], acc[mi][ni], 0, 0, 0);
    }
    asm volatile("s_waitcnt vmcnt(0)" ::: "memory");
    __syncthreads();
  }

  float eqv[4];
#pragma unroll
  for (int ni = 0; ni < 4; ++ni) eqv[ni] = esq[n0 + wc * 64 + ni * 16 + lrow];
  const int g = nb * 4 + wc;
#pragma unroll
  for (int mi = 0; mi < 8; ++mi) {
#pragma unroll
    for (int j = 0; j < 4; ++j) {
      int row = q0 + wr * 128 + mi * 16 + lkhi * 4 + j;
      float xq = xsq[row];
      u64 bst = ~0ull;
#pragma unroll
      for (int ni = 0; ni < 4; ++ni) {
        float d = (xq + eqv[ni]) - 2.0f * acc[mi][ni][j];
        int k = n0 + wc * 64 + ni * 16 + lrow;
        u64 p = ((u64)__float_as_uint(d) << 32) | (unsigned)k;
        if (p < bst) bst = p;
      }
#pragma unroll
      for (int m = 1; m <= 8; m <<= 1) {
        u64 o = __shfl_xor(bst, m);
        if (o < bst) bst = o;
      }
      if (lrow == 0)
        mins_t[(size_t)g * N_Q + row] = __uint_as_float((unsigned)(bst >> 32));
    }
  }
}

// ===========================================================================
// thr[q] = min_g mins_t[g][q] + MARGIN; also zero counters. (No atomics in
// the loop -> compiler pipelines the 256 loads; was fast in R9-R12.)
// ===========================================================================
__global__ __launch_bounds__(256) void vq_thr(const float* __restrict__ mins_t,
                                              float* __restrict__ thr,
                                              int* __restrict__ gcnt,
                                              int* __restrict__ gcursor,
                                              int* __restrict__ meta) {
  int q = blockIdx.x * 256 + threadIdx.x;
  float m = 3.4e38f;
  for (int g = 0; g < NGRAN; ++g) m = fminf(m, mins_t[(size_t)g * N_Q + q]);
  thr[q] = m + MARGIN;
  if (q < NGRAN) { gcnt[q] = 0; gcursor[q] = 0; }
  if (q < 4) meta[q] = 0;
}

// ===========================================================================
// hist v2 — block per granule, coalesced row scan (32 unrollable iters, no
// atomics in loop), wave reduce + LDS reduce -> gcnt[g]. Replaces R13's
// serial-granule-loop version (180us-class anti-pattern).
// ===========================================================================
__global__ __launch_bounds__(256) void vq_hist(const float* __restrict__ mins_t,
                                               const float* __restrict__ thr,
                                               int* __restrict__ gcnt) {
  __shared__ int wsum[4];
  const int g = blockIdx.x;
  const int tid = threadIdx.x;
  const float* mrow = mins_t + (size_t)g * N_Q;
  int cnt = 0;
  for (int c = tid; c < N_Q; c += 256)
    if (mrow[c] <= thr[c]) ++cnt;
#pragma unroll
  for (int s = 1; s <= 32; s <<= 1) cnt += __shfl_xor(cnt, s);
  if ((tid & 63) == 0) wsum[tid >> 6] = cnt;
  __syncthreads();
  if (tid == 0) gcnt[g] = ((wsum[0] + wsum[1]) + wsum[2]) + wsum[3];
}

// ===========================================================================
// chunks (R13-verified): 1 block; prefix sums -> goff + uniform <=64-pair
// chunk descriptors; overflow -> mode=1.
// ===========================================================================
__global__ __launch_bounds__(256) void vq_chunks(const int* __restrict__ gcnt,
                                                 int* __restrict__ goff,
                                                 unsigned* __restrict__ chunks,
                                                 int* __restrict__ meta) {
  __shared__ int cnt[NGRAN], off[NGRAN + 1], nch[NGRAN], choff[NGRAN + 1];
  const int tid = threadIdx.x;
  cnt[tid] = gcnt[tid];
  __syncthreads();
  if (tid == 0) {
    int s = 0;
    for (int g = 0; g < NGRAN; ++g) { off[g] = s; s += cnt[g]; }
    off[NGRAN] = s;
  }
  __syncthreads();
  nch[tid] = (cnt[tid] + 63) >> 6;
  __syncthreads();
  if (tid == 0) {
    int s = 0;
    for (int g = 0; g < NGRAN; ++g) { choff[g] = s; s += nch[g]; }
    choff[NGRAN] = s;
  }
  __syncthreads();
  const int P = off[NGRAN];
  const int C = choff[NGRAN];
  goff[tid] = off[tid];
  if (tid == 0) {
    goff[NGRAN] = P;
    meta[0] = P;
    meta[1] = (P > PCAP || C > CCAP) ? 2048 : C;
    meta[2] = (P > PCAP || C > CCAP) ? 1 : 0;
  }
  if (!(P > PCAP || C > CCAP)) {
    for (int c = 0; c < nch[tid]; ++c)
      chunks[choff[tid] + c] = ((unsigned)tid << 20) | (unsigned)(c * 64);
  }
}

// ===========================================================================
// scatter v2 — block per (granule, 1024-query slice), grid (256, 8).
// Coalesced row scan -> LDS compaction -> ONE global atomicAdd reserves a
// contiguous segment -> bulk coalesced copy. Intra-granule order is a
// run-varying permutation, but the pair SET is exact and the final
// atomicMin merge is order-invariant -> deterministic output.
// ===========================================================================
__global__ __launch_bounds__(256) void vq_scatter(
    const float* __restrict__ mins_t, const float* __restrict__ thr,
    const int* __restrict__ goff, int* __restrict__ gcursor,
    int* __restrict__ plist) {
  __shared__ int lbuf[RQB];
  __shared__ int lcnt;
  __shared__ int base;
  const int g = blockIdx.x;
  const int q0 = blockIdx.y * RQB;
  const int tid = threadIdx.x;
  if (tid == 0) lcnt = 0;
  __syncthreads();
  const float* mrow = mins_t + (size_t)g * N_Q + q0;
  for (int c = tid; c < RQB; c += 256) {
    if (mrow[c] <= thr[q0 + c]) {
      int pos = atomicAdd(&lcnt, 1);
      lbuf[pos] = q0 + c;
    }
  }
  __syncthreads();
  if (tid == 0) base = atomicAdd(&gcursor[g], lcnt);
  __syncthreads();
  const int b0 = goff[g] + base;
  for (int i = tid; i < lcnt; i += 256) {
    int idx = b0 + i;
    if (idx < PCAP) plist[idx] = lbuf[i];
  }
}

// ===========================================================================
// rescore_c (R13-verified): grid-stride over uniform chunks (<=64 pairs, one
// granule). Stage codes once (cL[64][257], (l+c)%32 -> 2-way free), 4 waves x
// 8-query-ILP EXACT R1 fmaf chains, u64 atomicMin -> packed2. mode==1
// fallback = R12-style scan (correct, slower; not expected to trigger).
// ===========================================================================
__global__ __launch_bounds__(256) void vq_rescore_c(
    const float* __restrict__ xt, const float* __restrict__ cb,
    const float* __restrict__ xsq, const float* __restrict__ esq,
    const float* __restrict__ mins_t, const float* __restrict__ thr,
    const int* __restrict__ goff, const int* __restrict__ gcnt,
    const int* __restrict__ plist, const unsigned* __restrict__ chunks,
    const int* __restrict__ meta, u64* __restrict__ packed2) {
  __shared__ float cL[GRAN][C_DIM + 1];  // 64.25KB
  __shared__ int lbuf[RQB];              // fallback worklist (4KB)
  __shared__ int lcnt;
  const int tid = threadIdx.x;
  const int w = tid >> 6;
  const int l = tid & 63;
  const int mode = meta[2];
  const int C = meta[1];

  if (mode == 0) {
    for (int ci = blockIdx.x; ci < C; ci += gridDim.x) {
      unsigned desc = chunks[ci];
      const int g = desc >> 20;
      const int s0 = desc & 0xFFFFF;
      const int n = min(64, gcnt[g] - s0);
      __syncthreads();  // protect cL from previous chunk's readers
      {  // stage granule codes
        const int kk = tid >> 2;
        const int seg = tid & 3;
        const float4* row = (const float4*)(cb + (size_t)(g * GRAN + kk) * C_DIM);
#pragma unroll
        for (int i = 0; i < 16; ++i) {
          int c4 = seg * 16 + i;
          float4 v = row[c4];
          cL[kk][c4 * 4 + 0] = v.x;
          cL[kk][c4 * 4 + 1] = v.y;
          cL[kk][c4 * 4 + 2] = v.z;
          cL[kk][c4 * 4 + 3] = v.w;
        }
      }
      __syncthreads();
      const int k = g * GRAN + l;
      const float eq = esq[k];
      const float* cr = &cL[l][0];
      const int base = goff[g] + s0;
      for (int i0 = w * 8; i0 < n; i0 += 32) {
        int qi[8];
#pragma unroll
        for (int j = 0; j < 8; ++j) {
          int ii = i0 + j;
          qi[j] = plist[base + (ii < n ? ii : n - 1)];
        }
        const float4* xp[8];
#pragma unroll
        for (int j = 0; j < 8; ++j)
          xp[j] = (const float4*)(xt + (size_t)qi[j] * C_DIM);
        float a[8];
#pragma unroll
        for (int j = 0; j < 8; ++j) a[j] = 0.f;
#pragma unroll 2
        for (int c4 = 0; c4 < 64; ++c4) {
          float e0 = cr[c4 * 4 + 0];
          float e1 = cr[c4 * 4 + 1];
          float e2 = cr[c4 * 4 + 2];
          float e3 = cr[c4 * 4 + 3];
#pragma unroll
          for (int j = 0; j < 8; ++j) {
            float4 v = xp[j][c4];
            float t = a[j];
            t = fmaf(v.x, e0, t);
            t = fmaf(v.y, e1, t);
            t = fmaf(v.z, e2, t);
            t = fmaf(v.w, e3, t);
            a[j] = t;
          }
        }
#pragma unroll
        for (int j = 0; j < 8; ++j) {
          float d = (xsq[qi[j]] + eq) - 2.0f * a[j];
          u64 p = ((u64)__float_as_uint(d) << 32) | (unsigned)k;
#pragma unroll
          for (int s = 1; s <= 32; s <<= 1) {
            u64 o = __shfl_xor(p, s);
            if (o < p) p = o;
          }
          if (l == 0) atomicMin(&packed2[qi[j]], p);
        }
      }
    }
    return;
  }

  // --------- fallback mode (P > PCAP): R12-style, correct, slow ---------
  if (blockIdx.x >= 2048) return;
  const int g = blockIdx.x >> 3;
  const int qbase = (blockIdx.x & 7) * RQB;
  if (tid == 0) lcnt = 0;
  __syncthreads();
  const float* mrow = mins_t + (size_t)g * N_Q + qbase;
  for (int c = tid; c < RQB; c += 256) {
    if (mrow[c] <= thr[qbase + c]) {
      int pos = atomicAdd(&lcnt, 1);
      lbuf[pos] = qbase + c;
    }
  }
  __syncthreads();
  const int n = lcnt;
  if (n == 0) return;
  {
    const int kk = tid >> 2;
    const int seg = tid & 3;
    const float4* row = (const float4*)(cb + (size_t)(g * GRAN + kk) * C_DIM);
#pragma unroll
    for (int i = 0; i < 16; ++i) {
      int c4 = seg * 16 + i;
      float4 v = row[c4];
      cL[kk][c4 * 4 + 0] = v.x;
      cL[kk][c4 * 4 + 1] = v.y;
      cL[kk][c4 * 4 + 2] = v.z;
      cL[kk][c4 * 4 + 3] = v.w;
    }
  }
  __syncthreads();
  const int k = g * GRAN + l;
  const float eq = esq[k];
  const float* cr = &cL[l][0];
  for (int i0 = w * 8; i0 < n; i0 += 32) {
    int qi[8];
#pragma unroll
    for (int j = 0; j < 8; ++j) {
      int ii = i0 + j;
      qi[j] = lbuf[ii < n ? ii : n - 1];
    }
    const float4* xp[8];
#pragma unroll
    for (int j = 0; j < 8; ++j)
      xp[j] = (const float4*)(xt + (size_t)qi[j] * C_DIM);
    float a[8];
#pragma unroll
    for (int j = 0; j < 8; ++j) a[j] = 0.f;
#pragma unroll 2
    for (int c4 = 0; c4 < 64; ++c4) {
      float e0 = cr[c4 * 4 + 0];
      float e1 = cr[c4 * 4 + 1];
      float e2 = cr[c4 * 4 + 2];
      float e3 = cr[c4 * 4 + 3];
#pragma unroll
      for (int j = 0; j < 8; ++j) {
        float4 v = xp[j][c4];
        float t = a[j];
        t = fmaf(v.x, e0, t);
        t = fmaf(v.y, e1, t);
        t = fmaf(v.z, e2, t);
        t = fmaf(v.w, e3, t);
        a[j] = t;
      }
    }
#pragma unroll
    for (int j = 0; j < 8; ++j) {
      float d = (xsq[qi[j]] + eq) - 2.0f * a[j];
      u64 p = ((u64)__float_as_uint(d) << 32) | (unsigned)k;
#pragma unroll
      for (int s = 1; s <= 32; s <<= 1) {
        u64 o = __shfl_xor(p, s);
        if (o < p) p = o;
      }
      if (l == 0) atomicMin(&packed2[qi[j]], p);
    }
  }
}

__global__ __launch_bounds__(256) void vq_out(const u64* __restrict__ packed2,
                                              int* __restrict__ out) {
  int n = blockIdx.x * 256 + threadIdx.x;
  if (n < N_Q) out[n] = (int)(unsigned)(packed2[n] & 0xffffffffull);
}

// ===========================================================================
// Fallback (R1, known-pass) if ws too small.
// ===========================================================================
#define TQ 64
#define TK 64
#define R1_NCH 8
#define R1_KCHUNK (N_K / R1_NCH)

__global__ __launch_bounds__(256) void r1_esq(const float* __restrict__ cb,
                                              float* __restrict__ esq) {
  int k = blockIdx.x * blockDim.x + threadIdx.x;
  if (k >= N_K) return;
  const float4* row = reinterpret_cast<const float4*>(cb + (size_t)k * C_DIM);
  float s = 0.f;
#pragma unroll 8
  for (int c4 = 0; c4 < C_DIM / 4; ++c4) {
    float4 v = row[c4];
    s = fmaf(v.x, v.x, s); s = fmaf(v.y, v.y, s);
    s = fmaf(v.z, v.z, s); s = fmaf(v.w, v.w, s);
  }
  esq[k] = s;
}

__global__ __launch_bounds__(256) void r1_main(
    const float* __restrict__ hidden, const float* __restrict__ cb,
    const float* __restrict__ esq, float* __restrict__ ws_d,
    int* __restrict__ ws_k) {
  __shared__ __align__(16) float xs[C_DIM][TQ + 4];
  __shared__ __align__(16) float es[TK][C_DIM + 4];
  __shared__ float xsq_part[4][TQ];
  __shared__ float xsq[TQ];
  __shared__ float red_d[16][TQ];
  __shared__ int red_k[16][TQ];
  const int tid = threadIdx.x;
  const int q0 = blockIdx.x * TQ;
  const int b = q0 >> 10;
  const int hw0 = q0 & 1023;
  const float* hb = hidden + (size_t)b * (C_DIM * 1024) + hw0;
  for (int idx = tid; idx < C_DIM * TQ; idx += 256) {
    int c = idx >> 6, q = idx & 63;
    xs[c][q] = hb[c * 1024 + q];
  }
  __syncthreads();
  {
    int q = tid & 63, part = tid >> 6, cbase = part * 64;
    float s = 0.f;
    for (int c = 0; c < 64; ++c) { float v = xs[cbase + c][q]; s = fmaf(v, v, s); }
    xsq_part[part][q] = s;
  }
  __syncthreads();
  if (tid < TQ)
    xsq[tid] = ((xsq_part[0][tid] + xsq_part[1][tid]) + xsq_part[2][tid]) + xsq_part[3][tid];
  __syncthreads();
  const int qt = tid & 15, kt = tid >> 4;
  float xsq_r[4];
#pragma unroll
  for (int i = 0; i < 4; ++i) xsq_r[i] = xsq[qt * 4 + i];
  float bd[4]; int bk[4];
#pragma unroll
  for (int i = 0; i < 4; ++i) { bd[i] = 3.4e38f; bk[i] = 0x7fffffff; }
  const int kbegin = blockIdx.y * R1_KCHUNK;
  for (int kt0 = kbegin; kt0 < kbegin + R1_KCHUNK; kt0 += TK) {
    __syncthreads();
    for (int idx = tid; idx < TK * (C_DIM / 4); idx += 256) {
      int kk = idx >> 6, c4 = idx & 63;
      float4 v = reinterpret_cast<const float4*>(cb + (size_t)(kt0 + kk) * C_DIM)[c4];
      es[kk][c4 * 4 + 0] = v.x; es[kk][c4 * 4 + 1] = v.y;
      es[kk][c4 * 4 + 2] = v.z; es[kk][c4 * 4 + 3] = v.w;
    }
    __syncthreads();
    float acc[4][4];
#pragma unroll
    for (int i = 0; i < 4; ++i)
#pragma unroll
      for (int j = 0; j < 4; ++j) acc[i][j] = 0.f;
    for (int c4 = 0; c4 < C_DIM; c4 += 4) {
      float4 xv0 = *reinterpret_cast<const float4*>(&xs[c4 + 0][qt * 4]);
      float4 xv1 = *reinterpret_cast<const float4*>(&xs[c4 + 1][qt * 4]);
      float4 xv2 = *reinterpret_cast<const float4*>(&xs[c4 + 2][qt * 4]);
      float4 xv3 = *reinterpret_cast<const float4*>(&xs[c4 + 3][qt * 4]);
      float xq0[4] = {xv0.x, xv0.y, xv0.z, xv0.w};
      float xq1[4] = {xv1.x, xv1.y, xv1.z, xv1.w};
      float xq2[4] = {xv2.x, xv2.y, xv2.z, xv2.w};
      float xq3[4] = {xv3.x, xv3.y, xv3.z, xv3.w};
      float4 ev[4];
#pragma unroll
      for (int j = 0; j < 4; ++j)
        ev[j] = *reinterpret_cast<const float4*>(&es[kt * 4 + j][c4]);
#pragma unroll
      for (int i = 0; i < 4; ++i) {
#pragma unroll
        for (int j = 0; j < 4; ++j) {
          float a = acc[i][j];
          a = fmaf(xq0[i], ev[j].x, a);
          a = fmaf(xq1[i], ev[j].y, a);
          a = fmaf(xq2[i], ev[j].z, a);
          a = fmaf(xq3[i], ev[j].w, a);
          acc[i][j] = a;
        }
      }
    }
#pragma unroll
    for (int j = 0; j < 4; ++j) {
      int k = kt0 + kt * 4 + j;
      float eq = esq[k];
#pragma unroll
      for (int i = 0; i < 4; ++i) {
        float t1 = xsq_r[i] + eq;
        float d = t1 - 2.0f * acc[i][j];
        if (d < bd[i]) { bd[i] = d; bk[i] = k; }
      }
    }
  }
#pragma unroll
  for (int i = 0; i < 4; ++i) {
    red_d[kt][qt * 4 + i] = bd[i];
    red_k[kt][qt * 4 + i] = bk[i];
  }
  __syncthreads();
  if (tid < TQ) {
    float d = red_d[0][tid]; int kb = red_k[0][tid];
    for (int t = 1; t < 16; ++t) {
      float dn = red_d[t][tid]; int kn = red_k[t][tid];
      if (dn < d || (dn == d && kn < kb)) { d = dn; kb = kn; }
    }
    int q = q0 + tid;
    ws_d[(size_t)q * R1_NCH + blockIdx.y] = d;
    ws_k[(size_t)q * R1_NCH + blockIdx.y] = kb;
  }
}

__global__ __launch_bounds__(256) void r1_final(
    const float* __restrict__ ws_d, const int* __restrict__ ws_k,
    int* __restrict__ out) {
  int n = blockIdx.x * blockDim.x + threadIdx.x;
  if (n >= N_Q) return;
  const float* dp = ws_d + (size_t)n * R1_NCH;
  const int* kp = ws_k + (size_t)n * R1_NCH;
  float d = dp[0]; int kb = kp[0];
#pragma unroll
  for (int j = 1; j < R1_NCH; ++j) {
    float dn = dp[j]; int kn = kp[j];
    if (dn < d || (dn == d && kn < kb)) { d = dn; kb = kn; }
  }
  out[n] = kb;
}

extern "C" void kernel_launch(void* const* d_in, const int* in_sizes, int n_in,
                              void* d_out, int out_size, void* d_ws,
                              size_t ws_size, hipStream_t stream) {
  const float* hidden = (const float*)d_in[0];
  const float* cb = (const float*)d_in[1];
  int* out = (int*)d_out;

  const size_t MB = 1024 * 1024;
  const size_t KB = 1024;
  const size_t NEED = 29 * MB;  // proven available (R3/R5-R13 passed)

  if (ws_size >= NEED) {
    char* w = (char*)d_ws;
    unsigned short* xb = (unsigned short*)(w);                 // 4MB
    unsigned short* eb = (unsigned short*)(w + 4 * MB);        // 8MB
    float* xt = (float*)(w + 12 * MB);                         // 8MB
    float* mins_t = (float*)(w + 20 * MB);                     // 8MB [g][q]
    char* s = w + 28 * MB;                                     // 1MB small pool
    float* xsq = (float*)(s);                                  // 32KB
    float* thr = (float*)(s + 32 * KB);                        // 32KB
    float* esq = (float*)(s + 64 * KB);                        // 64KB
    u64* packed2 = (u64*)(s + 128 * KB);                       // 64KB
    int* gcnt = (int*)(s + 192 * KB);                          // 1KB
    int* gcursor = (int*)(s + 193 * KB);                       // 1KB
    int* goff = (int*)(s + 194 * KB);                          // 2KB
    int* meta = (int*)(s + 196 * KB);                          // 1KB
    unsigned* chunks = (unsigned*)(s + 197 * KB);              // 16KB
    int* plist = (int*)(s + 213 * KB);                         // ~800KB (PCAP)

    vq_pre_x<<<dim3(256), dim3(256), 0, stream>>>(hidden, xt, xb, xsq, packed2);
    vq_pre_e<<<dim3(N_K / 64), dim3(256), 0, stream>>>(cb, eb, esq);
    vq_gemm<<<dim3((N_Q / BM) * (N_K / BN)), dim3(512), 0, stream>>>(
        xb, eb, xsq, esq, mins_t);
    vq_thr<<<dim3(N_Q / 256), dim3(256), 0, stream>>>(mins_t, thr, gcnt,
                                                      gcursor, meta);
    vq_hist<<<dim3(NGRAN), dim3(256), 0, stream>>>(mins_t, thr, gcnt);
    vq_chunks<<<dim3(1), dim3(256), 0, stream>>>(gcnt, goff, chunks, meta);
    vq_scatter<<<dim3(NGRAN, N_Q / RQB), dim3(256), 0, stream>>>(
        mins_t, thr, goff, gcursor, plist);
    vq_rescore_c<<<dim3(4096), dim3(256), 0, stream>>>(
        xt, cb, xsq, esq, mins_t, thr, goff, gcnt, plist, chunks, meta,
        packed2);
    vq_out<<<dim3(N_Q / 256), dim3(256), 0, stream>>>(packed2, out);
  } else {
    float* esq_f = (float*)d_ws;
    float* ws_d = (float*)((char*)d_ws + 65536);
    int* ws_k = (int*)((char*)d_ws + 65536 + N_Q * R1_NCH * 4);
    r1_esq<<<dim3(N_K / 256), dim3(256), 0, stream>>>(cb, esq_f);
    r1_main<<<dim3(N_Q / TQ, R1_NCH), dim3(256), 0, stream>>>(hidden, cb, esq_f, ws_d, ws_k);
    r1_final<<<dim3(N_Q / 256), dim3(256), 0, stream>>>(ws_d, ws_k, out);
  }
}

// Round 15
// 306.452 us; speedup vs baseline: 1.7852x; 1.1646x over previous
//
#include <hip/hip_runtime.h>

#define N_Q 8192
#define N_K 16384
#define C_DIM 256
#define BM 256
#define BN 256
#define BK 64
#define NGRAN 256   // 64-code granules
#define GRAN 64
// Rigorous worst-case |d_approx - d_np| <= 1.9e-4; flagging needs 2x = 3.8e-4.
#define MARGIN 4.5e-4f
#define PCAP 200000      // pair-list capacity (overflow -> fallback mode)
#define CCAP 4096        // chunk descriptor capacity
#define RQB 1024         // fallback-mode / scatter slice size

typedef __attribute__((ext_vector_type(8))) short short8;
typedef __attribute__((ext_vector_type(4))) float f32x4;
typedef __attribute__((ext_vector_type(4))) unsigned short ushort4_t;
typedef unsigned long long u64;

__device__ inline unsigned short f2bf(float f) {  // RNE fp32->bf16 (finite)
  unsigned u = __float_as_uint(f);
  return (unsigned short)((u + 0x7fffu + ((u >> 16) & 1u)) >> 16);
}

__device__ inline void gl_lds16(const void* g, void* l) {
  __builtin_amdgcn_global_load_lds(
      (const __attribute__((address_space(1))) unsigned int*)g,
      (__attribute__((address_space(3))) unsigned int*)l, 16, 0, 0);
}

// ===========================================================================
// pre_x (R11-verified): LDS-tile transpose; exact R1 xsq order; init packed2.
// ===========================================================================
__global__ __launch_bounds__(256) void vq_pre_x(
    const float* __restrict__ hidden, float* __restrict__ xt,
    unsigned short* __restrict__ xb, float* __restrict__ xsq,
    u64* __restrict__ packed2) {
  __shared__ float xs[C_DIM][36];
  __shared__ float xsq_part[4][32];
  const int tile = blockIdx.x;       // 256 = 8 b x 32 hw-tiles
  const int b = tile >> 5;
  const int hw0 = (tile & 31) * 32;
  const int q0 = b * 1024 + hw0;
  const float* hb = hidden + (size_t)b * (C_DIM * 1024) + hw0;
  const int tid = threadIdx.x;

  for (int idx = tid; idx < C_DIM * 32; idx += 256) {
    int c = idx >> 5, q = idx & 31;
    xs[c][q] = hb[c * 1024 + q];     // coalesced over q
  }
  __syncthreads();

  if (tid < 128) {  // xsq partials, exact R1 c-ranges
    int q = tid & 31, part = tid >> 5, cb0 = part * 64;
    float s = 0.f;
    for (int c = 0; c < 64; ++c) { float v = xs[cb0 + c][q]; s = fmaf(v, v, s); }
    xsq_part[part][q] = s;
  }
  __syncthreads();
  if (tid < 32) {
    xsq[q0 + tid] = ((xsq_part[0][tid] + xsq_part[1][tid]) + xsq_part[2][tid]) +
                    xsq_part[3][tid];
    packed2[q0 + tid] = ~0ull;
  }

  {  // xt + xb row writes
    int q = tid >> 3, c0 = (tid & 7) * 32;
    float* xo = xt + (size_t)(q0 + q) * C_DIM + c0;
    unsigned short* bo = xb + (size_t)(q0 + q) * C_DIM + c0;
    for (int i = 0; i < 32; i += 4) {
      float4 v = {xs[c0 + i][q], xs[c0 + i + 1][q], xs[c0 + i + 2][q],
                  xs[c0 + i + 3][q]};
      *reinterpret_cast<float4*>(xo + i) = v;
      ushort4_t bv = {f2bf(v.x), f2bf(v.y), f2bf(v.z), f2bf(v.w)};
      *reinterpret_cast<ushort4_t*>(bo + i) = bv;
    }
  }
}

// ===========================================================================
// pre_e (R11-verified): coalesced staging; exact R1 esq chain; eb bf16.
// ===========================================================================
__global__ __launch_bounds__(256) void vq_pre_e(
    const float* __restrict__ cb, unsigned short* __restrict__ eb,
    float* __restrict__ esq) {
  __shared__ float es[64][257];
  const int k0 = blockIdx.x * 64;
  const int tid = threadIdx.x;

  for (int idx = tid; idx < 64 * 64; idx += 256) {
    int kk = idx >> 6, c4 = idx & 63;
    float4 v = reinterpret_cast<const float4*>(cb + (size_t)(k0 + kk) * C_DIM)[c4];
    es[kk][c4 * 4 + 0] = v.x; es[kk][c4 * 4 + 1] = v.y;
    es[kk][c4 * 4 + 2] = v.z; es[kk][c4 * 4 + 3] = v.w;
  }
  __syncthreads();

  if (tid < 64) {
    float s = 0.f;
    for (int c = 0; c < 256; ++c) { float v = es[tid][c]; s = fmaf(v, v, s); }
    esq[k0 + tid] = s;
  }

  {  // eb writes coalesced
    int r = tid >> 2, c0 = (tid & 3) * 64;
    unsigned short* bo = eb + (size_t)(k0 + r) * C_DIM + c0;
    for (int i = 0; i < 64; i += 4) {
      ushort4_t bv = {f2bf(es[r][c0 + i]), f2bf(es[r][c0 + i + 1]),
                      f2bf(es[r][c0 + i + 2]), f2bf(es[r][c0 + i + 3])};
      *reinterpret_cast<ushort4_t*>(bo + i) = bv;
    }
  }
}

// ===========================================================================
// Prefilter GEMM — exact R9/R11 config (verified 147us, conflicts=0).
// ===========================================================================
__global__ __launch_bounds__(512) void vq_gemm(
    const unsigned short* __restrict__ xb, const unsigned short* __restrict__ eb,
    const float* __restrict__ xsq, const float* __restrict__ esq,
    float* __restrict__ mins_t) {
  __shared__ __align__(16) unsigned short As[2][BM * BK];
  __shared__ __align__(16) unsigned short Bs[2][BN * BK];

  const int tid = threadIdx.x;
  const int wid = tid >> 6;
  const int lane = tid & 63;

  int bidx = blockIdx.x;
  int xcd = bidx & 7;
  int idx = bidx >> 3;
  int nb = xcd * 8 + (idx >> 5);
  int qb = idx & 31;
  const int q0 = qb * BM;
  const int n0 = nb * BN;

  const int wr = wid >> 2, wc = wid & 3;
  const int lrow = lane & 15;
  const int lkhi = lane >> 4;
  const int srow = lane >> 3;
  const int sseg = (lane & 7) ^ srow;

  auto stage = [&](int kt, int bf) {
#pragma unroll
    for (int i = 0; i < 4; ++i) {
      int r0 = (wid * 4 + i) * 8;
      gl_lds16(xb + (size_t)(q0 + r0 + srow) * C_DIM + kt * BK + sseg * 8,
               (void*)((char*)&As[bf][0] + (size_t)r0 * BK * 2));
      gl_lds16(eb + (size_t)(n0 + r0 + srow) * C_DIM + kt * BK + sseg * 8,
               (void*)((char*)&Bs[bf][0] + (size_t)r0 * BK * 2));
    }
  };

  f32x4 acc[8][4];
#pragma unroll
  for (int i = 0; i < 8; ++i)
#pragma unroll
    for (int j = 0; j < 4; ++j) acc[i][j] = (f32x4){0.f, 0.f, 0.f, 0.f};

  stage(0, 0);
  asm volatile("s_waitcnt vmcnt(0)" ::: "memory");
  __syncthreads();

  const int r7 = lrow & 7;
  for (int kt = 0; kt < C_DIM / BK; ++kt) {
    int bf = kt & 1;
    if (kt + 1 < C_DIM / BK) stage(kt + 1, bf ^ 1);
#pragma unroll
    for (int kk = 0; kk < 2; ++kk) {
      const int segA = ((kk * 4 + lkhi) ^ r7) * 8;
      short8 a[8], b[4];
#pragma unroll
      for (int mi = 0; mi < 8; ++mi)
        a[mi] = *(const short8*)((const char*)&As[bf][0] +
                 (size_t)((wr * 128 + mi * 16 + lrow) * BK + segA) * 2);
#pragma unroll
      for (int ni = 0; ni < 4; ++ni)
        b[ni] = *(const short8*)((const char*)&Bs[bf][0] +
                 (size_t)((wc * 64 + ni * 16 + lrow) * BK + segA) * 2);
#pragma unroll
      for (int mi = 0; mi < 8; ++mi)
#pragma unroll
        for (int ni = 0; ni < 4; ++ni)
          acc[mi][ni] = __builtin_amdgcn_mfma_f32_16x16x32_bf16(
              a[mi], b[ni], acc[mi][ni], 0, 0, 0);
    }
    asm volatile("s_waitcnt vmcnt(0)" ::: "memory");
    __syncthreads();
  }

  float eqv[4];
#pragma unroll
  for (int ni = 0; ni < 4; ++ni) eqv[ni] = esq[n0 + wc * 64 + ni * 16 + lrow];
  const int g = nb * 4 + wc;
#pragma unroll
  for (int mi = 0; mi < 8; ++mi) {
#pragma unroll
    for (int j = 0; j < 4; ++j) {
      int row = q0 + wr * 128 + mi * 16 + lkhi * 4 + j;
      float xq = xsq[row];
      u64 bst = ~0ull;
#pragma unroll
      for (int ni = 0; ni < 4; ++ni) {
        float d = (xq + eqv[ni]) - 2.0f * acc[mi][ni][j];
        int k = n0 + wc * 64 + ni * 16 + lrow;
        u64 p = ((u64)__float_as_uint(d) << 32) | (unsigned)k;
        if (p < bst) bst = p;
      }
#pragma unroll
      for (int m = 1; m <= 8; m <<= 1) {
        u64 o = __shfl_xor(bst, m);
        if (o < bst) bst = o;
      }
      if (lrow == 0)
        mins_t[(size_t)g * N_Q + row] = __uint_as_float((unsigned)(bst >> 32));
    }
  }
}

// ===========================================================================
// thr v2 — 256 blocks x 32 queries, 8-way cooperative column-min; zero
// counters. Coalesced (32 consecutive q per granule-row read).
// ===========================================================================
__global__ __launch_bounds__(256) void vq_thr(const float* __restrict__ mins_t,
                                              float* __restrict__ thr,
                                              int* __restrict__ gcnt,
                                              int* __restrict__ gcursor,
                                              int* __restrict__ meta) {
  __shared__ float pm[8][32];
  const int q0 = blockIdx.x * 32;
  const int tid = threadIdx.x;
  const int ql = tid & 31;
  const int part = tid >> 5;
  float m = 3.4e38f;
  for (int g = part * 32; g < part * 32 + 32; ++g)
    m = fminf(m, mins_t[(size_t)g * N_Q + q0 + ql]);
  pm[part][ql] = m;
  __syncthreads();
  if (tid < 32) {
    float mm = pm[0][tid];
#pragma unroll
    for (int p = 1; p < 8; ++p) mm = fminf(mm, pm[p][tid]);
    thr[q0 + tid] = mm + MARGIN;
  }
  int q = blockIdx.x * 32 + tid;  // stride-32 per block: covers 0..8191 once
  if (blockIdx.x < 8 && tid < 32) {
    int g = blockIdx.x * 32 + tid;
    gcnt[g] = 0;
    gcursor[g] = 0;
  }
  if (blockIdx.x == 0 && tid < 4) meta[tid] = 0;
  (void)q;
}

// ===========================================================================
// hist (R14-verified): block per granule, coalesced row scan, wave+LDS
// reduce -> gcnt[g].
// ===========================================================================
__global__ __launch_bounds__(256) void vq_hist(const float* __restrict__ mins_t,
                                               const float* __restrict__ thr,
                                               int* __restrict__ gcnt) {
  __shared__ int wsum[4];
  const int g = blockIdx.x;
  const int tid = threadIdx.x;
  const float* mrow = mins_t + (size_t)g * N_Q;
  int cnt = 0;
  for (int c = tid; c < N_Q; c += 256)
    if (mrow[c] <= thr[c]) ++cnt;
#pragma unroll
  for (int s = 1; s <= 32; s <<= 1) cnt += __shfl_xor(cnt, s);
  if ((tid & 63) == 0) wsum[tid >> 6] = cnt;
  __syncthreads();
  if (tid == 0) gcnt[g] = ((wsum[0] + wsum[1]) + wsum[2]) + wsum[3];
}

// ===========================================================================
// chunks (R13/R14-verified): 1 block; prefix sums -> goff + uniform <=64-pair
// chunk descriptors; overflow -> mode=1.
// ===========================================================================
__global__ __launch_bounds__(256) void vq_chunks(const int* __restrict__ gcnt,
                                                 int* __restrict__ goff,
                                                 unsigned* __restrict__ chunks,
                                                 int* __restrict__ meta) {
  __shared__ int cnt[NGRAN], off[NGRAN + 1], nch[NGRAN], choff[NGRAN + 1];
  const int tid = threadIdx.x;
  cnt[tid] = gcnt[tid];
  __syncthreads();
  if (tid == 0) {
    int s = 0;
    for (int g = 0; g < NGRAN; ++g) { off[g] = s; s += cnt[g]; }
    off[NGRAN] = s;
  }
  __syncthreads();
  nch[tid] = (cnt[tid] + 63) >> 6;
  __syncthreads();
  if (tid == 0) {
    int s = 0;
    for (int g = 0; g < NGRAN; ++g) { choff[g] = s; s += nch[g]; }
    choff[NGRAN] = s;
  }
  __syncthreads();
  const int P = off[NGRAN];
  const int C = choff[NGRAN];
  goff[tid] = off[tid];
  if (tid == 0) {
    goff[NGRAN] = P;
    meta[0] = P;
    meta[1] = (P > PCAP || C > CCAP) ? 2048 : C;
    meta[2] = (P > PCAP || C > CCAP) ? 1 : 0;
  }
  if (!(P > PCAP || C > CCAP)) {
    for (int c = 0; c < nch[tid]; ++c)
      chunks[choff[tid] + c] = ((unsigned)tid << 20) | (unsigned)(c * 64);
  }
}

// ===========================================================================
// scatter (R14-verified): block per (granule, 1024-query slice); coalesced
// scan -> LDS compaction -> one segment-reserve atomic -> bulk copy.
// ===========================================================================
__global__ __launch_bounds__(256) void vq_scatter(
    const float* __restrict__ mins_t, const float* __restrict__ thr,
    const int* __restrict__ goff, int* __restrict__ gcursor,
    int* __restrict__ plist) {
  __shared__ int lbuf[RQB];
  __shared__ int lcnt;
  __shared__ int base;
  const int g = blockIdx.x;
  const int q0 = blockIdx.y * RQB;
  const int tid = threadIdx.x;
  if (tid == 0) lcnt = 0;
  __syncthreads();
  const float* mrow = mins_t + (size_t)g * N_Q + q0;
  for (int c = tid; c < RQB; c += 256) {
    if (mrow[c] <= thr[q0 + c]) {
      int pos = atomicAdd(&lcnt, 1);
      lbuf[pos] = q0 + c;
    }
  }
  __syncthreads();
  if (tid == 0) base = atomicAdd(&gcursor[g], lcnt);
  __syncthreads();
  const int b0 = goff[g] + base;
  for (int i = tid; i < lcnt; i += 256) {
    int idx = b0 + i;
    if (idx < PCAP) plist[idx] = lbuf[i];
  }
}

// ===========================================================================
// rescore v7 — HALF-GRANULE chunks for 4x TLP. Block = (chunk ci, half h):
// stages 32 code rows (cL[32][257] = 32.1KB; total LDS ~37KB -> 4 blocks/CU
// = 16 waves/CU, 4x R14). Wave processes 2 queries at once (lanes 0-31 =
// entry A, 32-63 = entry B; cL reads broadcast across halves - free) x 8 ILP
// = 16 list entries per sweep. EXACT R1 fmaf chain per lane; 32-lane
// shfl_xor reduce (halves independent); lanes 0/32 atomicMin their query.
// ===========================================================================
__global__ __launch_bounds__(256) void vq_rescore_c(
    const float* __restrict__ xt, const float* __restrict__ cb,
    const float* __restrict__ xsq, const float* __restrict__ esq,
    const float* __restrict__ mins_t, const float* __restrict__ thr,
    const int* __restrict__ goff, const int* __restrict__ gcnt,
    const int* __restrict__ plist, const unsigned* __restrict__ chunks,
    const int* __restrict__ meta, u64* __restrict__ packed2) {
  __shared__ float cL[32][C_DIM + 1];  // 32.1KB (half granule)
  __shared__ int lbuf[RQB];            // fallback worklist (4KB)
  __shared__ int lcnt;
  const int tid = threadIdx.x;
  const int w = tid >> 6;
  const int l = tid & 63;
  const int cloc = l & 31;   // code within half
  const int hi = l >> 5;     // which query of the lane-pair
  const int h = blockIdx.y;  // half-granule
  const int mode = meta[2];
  const int C = meta[1];

  auto stage_half = [&](int g) {
    const int row = tid >> 3;          // 0..31
    const int seg = tid & 7;           // 8 float4 each
    const float4* rp =
        (const float4*)(cb + (size_t)(g * GRAN + h * 32 + row) * C_DIM);
#pragma unroll
    for (int i = 0; i < 8; ++i) {
      int c4 = seg * 8 + i;
      float4 v = rp[c4];
      cL[row][c4 * 4 + 0] = v.x;
      cL[row][c4 * 4 + 1] = v.y;
      cL[row][c4 * 4 + 2] = v.z;
      cL[row][c4 * 4 + 3] = v.w;
    }
  };

  auto sweep = [&](int g, const int* list, int base, int n) {
    const int k = g * GRAN + h * 32 + cloc;
    const float eq = esq[k];
    const float* cr = &cL[cloc][0];
    for (int i0 = w * 16; i0 < n; i0 += 64) {
      int qi[8];
#pragma unroll
      for (int j = 0; j < 8; ++j) {
        int ii = i0 + 2 * j + hi;
        qi[j] = list[base + (ii < n ? ii : n - 1)];  // clamp dup: idempotent
      }
      const float4* xp[8];
#pragma unroll
      for (int j = 0; j < 8; ++j)
        xp[j] = (const float4*)(xt + (size_t)qi[j] * C_DIM);
      float a[8];
#pragma unroll
      for (int j = 0; j < 8; ++j) a[j] = 0.f;
#pragma unroll 2
      for (int c4 = 0; c4 < 64; ++c4) {
        float e0 = cr[c4 * 4 + 0];
        float e1 = cr[c4 * 4 + 1];
        float e2 = cr[c4 * 4 + 2];
        float e3 = cr[c4 * 4 + 3];
#pragma unroll
        for (int j = 0; j < 8; ++j) {
          float4 v = xp[j][c4];  // 2 lines per instr (one per half)
          float t = a[j];
          t = fmaf(v.x, e0, t);
          t = fmaf(v.y, e1, t);
          t = fmaf(v.z, e2, t);
          t = fmaf(v.w, e3, t);
          a[j] = t;
        }
      }
#pragma unroll
      for (int j = 0; j < 8; ++j) {
        float d = (xsq[qi[j]] + eq) - 2.0f * a[j];
        u64 p = ((u64)__float_as_uint(d) << 32) | (unsigned)k;
#pragma unroll
        for (int s = 1; s <= 16; s <<= 1) {  // 32-lane reduce (halves split)
          u64 o = __shfl_xor(p, s);
          if (o < p) p = o;
        }
        if (cloc == 0) atomicMin(&packed2[qi[j]], p);
      }
    }
  };

  if (mode == 0) {
    for (int ci = blockIdx.x; ci < C; ci += gridDim.x) {
      unsigned desc = chunks[ci];
      const int g = desc >> 20;
      const int s0 = desc & 0xFFFFF;
      const int n = min(64, gcnt[g] - s0);
      __syncthreads();
      stage_half(g);
      __syncthreads();
      sweep(g, plist, goff[g] + s0, n);
    }
    return;
  }

  // --------- fallback mode (P > PCAP): half-granule window scan ---------
  if (blockIdx.x >= 2048) return;
  const int g = blockIdx.x >> 3;
  const int qbase = (blockIdx.x & 7) * RQB;
  if (tid == 0) lcnt = 0;
  __syncthreads();
  const float* mrow = mins_t + (size_t)g * N_Q + qbase;
  for (int c = tid; c < RQB; c += 256) {
    if (mrow[c] <= thr[qbase + c]) {
      int pos = atomicAdd(&lcnt, 1);
      lbuf[pos] = qbase + c;
    }
  }
  __syncthreads();
  const int n = lcnt;
  if (n == 0) return;
  stage_half(g);
  __syncthreads();
  sweep(g, lbuf, 0, n);
}

__global__ __launch_bounds__(256) void vq_out(const u64* __restrict__ packed2,
                                              int* __restrict__ out) {
  int n = blockIdx.x * 256 + threadIdx.x;
  if (n < N_Q) out[n] = (int)(unsigned)(packed2[n] & 0xffffffffull);
}

// ===========================================================================
// Fallback (R1, known-pass) if ws too small.
// ===========================================================================
#define TQ 64
#define TK 64
#define R1_NCH 8
#define R1_KCHUNK (N_K / R1_NCH)

__global__ __launch_bounds__(256) void r1_esq(const float* __restrict__ cb,
                                              float* __restrict__ esq) {
  int k = blockIdx.x * blockDim.x + threadIdx.x;
  if (k >= N_K) return;
  const float4* row = reinterpret_cast<const float4*>(cb + (size_t)k * C_DIM);
  float s = 0.f;
#pragma unroll 8
  for (int c4 = 0; c4 < C_DIM / 4; ++c4) {
    float4 v = row[c4];
    s = fmaf(v.x, v.x, s); s = fmaf(v.y, v.y, s);
    s = fmaf(v.z, v.z, s); s = fmaf(v.w, v.w, s);
  }
  esq[k] = s;
}

__global__ __launch_bounds__(256) void r1_main(
    const float* __restrict__ hidden, const float* __restrict__ cb,
    const float* __restrict__ esq, float* __restrict__ ws_d,
    int* __restrict__ ws_k) {
  __shared__ __align__(16) float xs[C_DIM][TQ + 4];
  __shared__ __align__(16) float es[TK][C_DIM + 4];
  __shared__ float xsq_part[4][TQ];
  __shared__ float xsq[TQ];
  __shared__ float red_d[16][TQ];
  __shared__ int red_k[16][TQ];
  const int tid = threadIdx.x;
  const int q0 = blockIdx.x * TQ;
  const int b = q0 >> 10;
  const int hw0 = q0 & 1023;
  const float* hb = hidden + (size_t)b * (C_DIM * 1024) + hw0;
  for (int idx = tid; idx < C_DIM * TQ; idx += 256) {
    int c = idx >> 6, q = idx & 63;
    xs[c][q] = hb[c * 1024 + q];
  }
  __syncthreads();
  {
    int q = tid & 63, part = tid >> 6, cbase = part * 64;
    float s = 0.f;
    for (int c = 0; c < 64; ++c) { float v = xs[cbase + c][q]; s = fmaf(v, v, s); }
    xsq_part[part][q] = s;
  }
  __syncthreads();
  if (tid < TQ)
    xsq[tid] = ((xsq_part[0][tid] + xsq_part[1][tid]) + xsq_part[2][tid]) + xsq_part[3][tid];
  __syncthreads();
  const int qt = tid & 15, kt = tid >> 4;
  float xsq_r[4];
#pragma unroll
  for (int i = 0; i < 4; ++i) xsq_r[i] = xsq[qt * 4 + i];
  float bd[4]; int bk[4];
#pragma unroll
  for (int i = 0; i < 4; ++i) { bd[i] = 3.4e38f; bk[i] = 0x7fffffff; }
  const int kbegin = blockIdx.y * R1_KCHUNK;
  for (int kt0 = kbegin; kt0 < kbegin + R1_KCHUNK; kt0 += TK) {
    __syncthreads();
    for (int idx = tid; idx < TK * (C_DIM / 4); idx += 256) {
      int kk = idx >> 6, c4 = idx & 63;
      float4 v = reinterpret_cast<const float4*>(cb + (size_t)(kt0 + kk) * C_DIM)[c4];
      es[kk][c4 * 4 + 0] = v.x; es[kk][c4 * 4 + 1] = v.y;
      es[kk][c4 * 4 + 2] = v.z; es[kk][c4 * 4 + 3] = v.w;
    }
    __syncthreads();
    float acc[4][4];
#pragma unroll
    for (int i = 0; i < 4; ++i)
#pragma unroll
      for (int j = 0; j < 4; ++j) acc[i][j] = 0.f;
    for (int c4 = 0; c4 < C_DIM; c4 += 4) {
      float4 xv0 = *reinterpret_cast<const float4*>(&xs[c4 + 0][qt * 4]);
      float4 xv1 = *reinterpret_cast<const float4*>(&xs[c4 + 1][qt * 4]);
      float4 xv2 = *reinterpret_cast<const float4*>(&xs[c4 + 2][qt * 4]);
      float4 xv3 = *reinterpret_cast<const float4*>(&xs[c4 + 3][qt * 4]);
      float xq0[4] = {xv0.x, xv0.y, xv0.z, xv0.w};
      float xq1[4] = {xv1.x, xv1.y, xv1.z, xv1.w};
      float xq2[4] = {xv2.x, xv2.y, xv2.z, xv2.w};
      float xq3[4] = {xv3.x, xv3.y, xv3.z, xv3.w};
      float4 ev[4];
#pragma unroll
      for (int j = 0; j < 4; ++j)
        ev[j] = *reinterpret_cast<const float4*>(&es[kt * 4 + j][c4]);
#pragma unroll
      for (int i = 0; i < 4; ++i) {
#pragma unroll
        for (int j = 0; j < 4; ++j) {
          float a = acc[i][j];
          a = fmaf(xq0[i], ev[j].x, a);
          a = fmaf(xq1[i], ev[j].y, a);
          a = fmaf(xq2[i], ev[j].z, a);
          a = fmaf(xq3[i], ev[j].w, a);
          acc[i][j] = a;
        }
      }
    }
#pragma unroll
    for (int j = 0; j < 4; ++j) {
      int k = kt0 + kt * 4 + j;
      float eq = esq[k];
#pragma unroll
      for (int i = 0; i < 4; ++i) {
        float t1 = xsq_r[i] + eq;
        float d = t1 - 2.0f * acc[i][j];
        if (d < bd[i]) { bd[i] = d; bk[i] = k; }
      }
    }
  }
#pragma unroll
  for (int i = 0; i < 4; ++i) {
    red_d[kt][qt * 4 + i] = bd[i];
    red_k[kt][qt * 4 + i] = bk[i];
  }
  __syncthreads();
  if (tid < TQ) {
    float d = red_d[0][tid]; int kb = red_k[0][tid];
    for (int t = 1; t < 16; ++t) {
      float dn = red_d[t][tid]; int kn = red_k[t][tid];
      if (dn < d || (dn == d && kn < kb)) { d = dn; kb = kn; }
    }
    int q = q0 + tid;
    ws_d[(size_t)q * R1_NCH + blockIdx.y] = d;
    ws_k[(size_t)q * R1_NCH + blockIdx.y] = kb;
  }
}

__global__ __launch_bounds__(256) void r1_final(
    const float* __restrict__ ws_d, const int* __restrict__ ws_k,
    int* __restrict__ out) {
  int n = blockIdx.x * blockDim.x + threadIdx.x;
  if (n >= N_Q) return;
  const float* dp = ws_d + (size_t)n * R1_NCH;
  const int* kp = ws_k + (size_t)n * R1_NCH;
  float d = dp[0]; int kb = kp[0];
#pragma unroll
  for (int j = 1; j < R1_NCH; ++j) {
    float dn = dp[j]; int kn = kp[j];
    if (dn < d || (dn == d && kn < kb)) { d = dn; kb = kn; }
  }
  out[n] = kb;
}

extern "C" void kernel_launch(void* const* d_in, const int* in_sizes, int n_in,
                              void* d_out, int out_size, void* d_ws,
                              size_t ws_size, hipStream_t stream) {
  const float* hidden = (const float*)d_in[0];
  const float* cb = (const float*)d_in[1];
  int* out = (int*)d_out;

  const size_t MB = 1024 * 1024;
  const size_t KB = 1024;
  const size_t NEED = 29 * MB;  // proven available (R3/R5-R14 passed)

  if (ws_size >= NEED) {
    char* w = (char*)d_ws;
    unsigned short* xb = (unsigned short*)(w);                 // 4MB
    unsigned short* eb = (unsigned short*)(w + 4 * MB);        // 8MB
    float* xt = (float*)(w + 12 * MB);                         // 8MB
    float* mins_t = (float*)(w + 20 * MB);                     // 8MB [g][q]
    char* s = w + 28 * MB;                                     // 1MB small pool
    float* xsq = (float*)(s);                                  // 32KB
    float* thr = (float*)(s + 32 * KB);                        // 32KB
    float* esq = (float*)(s + 64 * KB);                        // 64KB
    u64* packed2 = (u64*)(s + 128 * KB);                       // 64KB
    int* gcnt = (int*)(s + 192 * KB);                          // 1KB
    int* gcursor = (int*)(s + 193 * KB);                       // 1KB
    int* goff = (int*)(s + 194 * KB);                          // 2KB
    int* meta = (int*)(s + 196 * KB);                          // 1KB
    unsigned* chunks = (unsigned*)(s + 197 * KB);              // 16KB
    int* plist = (int*)(s + 213 * KB);                         // ~800KB (PCAP)

    vq_pre_x<<<dim3(256), dim3(256), 0, stream>>>(hidden, xt, xb, xsq, packed2);
    vq_pre_e<<<dim3(N_K / 64), dim3(256), 0, stream>>>(cb, eb, esq);
    vq_gemm<<<dim3((N_Q / BM) * (N_K / BN)), dim3(512), 0, stream>>>(
        xb, eb, xsq, esq, mins_t);
    vq_thr<<<dim3(N_Q / 32), dim3(256), 0, stream>>>(mins_t, thr, gcnt,
                                                     gcursor, meta);
    vq_hist<<<dim3(NGRAN), dim3(256), 0, stream>>>(mins_t, thr, gcnt);
    vq_chunks<<<dim3(1), dim3(256), 0, stream>>>(gcnt, goff, chunks, meta);
    vq_scatter<<<dim3(NGRAN, N_Q / RQB), dim3(256), 0, stream>>>(
        mins_t, thr, goff, gcursor, plist);
    vq_rescore_c<<<dim3(2048, 2), dim3(256), 0, stream>>>(
        xt, cb, xsq, esq, mins_t, thr, goff, gcnt, plist, chunks, meta,
        packed2);
    vq_out<<<dim3(N_Q / 256), dim3(256), 0, stream>>>(packed2, out);
  } else {
    float* esq_f = (float*)d_ws;
    float* ws_d = (float*)((char*)d_ws + 65536);
    int* ws_k = (int*)((char*)d_ws + 65536 + N_Q * R1_NCH * 4);
    r1_esq<<<dim3(N_K / 256), dim3(256), 0, stream>>>(cb, esq_f);
    r1_main<<<dim3(N_Q / TQ, R1_NCH), dim3(256), 0, stream>>>(hidden, cb, esq_f, ws_d, ws_k);
    r1_final<<<dim3(N_Q / 256), dim3(256), 0, stream>>>(ws_d, ws_k, out);
  }
}

// Round 16
// 258.373 us; speedup vs baseline: 2.1174x; 1.1861x over previous
//
#include <hip/hip_runtime.h>

#define N_Q 8192
#define N_K 16384
#define C_DIM 256
#define BM 128
#define BN 128
#define BK 64
#define NGRAN 256   // 64-code granules
#define GRAN 64
// Rigorous worst-case |d_approx - d_np| <= 1.9e-4; flagging needs 2x = 3.8e-4.
#define MARGIN 4.5e-4f
#define PCAP 200000      // pair-list capacity (overflow -> fallback mode)
#define CCAP 4096        // chunk descriptor capacity
#define RQB 1024         // fallback-mode / scatter slice size

typedef __attribute__((ext_vector_type(8))) short short8;
typedef __attribute__((ext_vector_type(4))) float f32x4;
typedef __attribute__((ext_vector_type(4))) unsigned short ushort4_t;
typedef unsigned long long u64;

__device__ inline unsigned short f2bf(float f) {  // RNE fp32->bf16 (finite)
  unsigned u = __float_as_uint(f);
  return (unsigned short)((u + 0x7fffu + ((u >> 16) & 1u)) >> 16);
}

__device__ inline void gl_lds16(const void* g, void* l) {
  __builtin_amdgcn_global_load_lds(
      (const __attribute__((address_space(1))) unsigned int*)g,
      (__attribute__((address_space(3))) unsigned int*)l, 16, 0, 0);
}

// ===========================================================================
// pre_x (R11-verified): LDS-tile transpose; exact R1 xsq order; init packed2.
// ===========================================================================
__global__ __launch_bounds__(256) void vq_pre_x(
    const float* __restrict__ hidden, float* __restrict__ xt,
    unsigned short* __restrict__ xb, float* __restrict__ xsq,
    u64* __restrict__ packed2) {
  __shared__ float xs[C_DIM][36];
  __shared__ float xsq_part[4][32];
  const int tile = blockIdx.x;       // 256 = 8 b x 32 hw-tiles
  const int b = tile >> 5;
  const int hw0 = (tile & 31) * 32;
  const int q0 = b * 1024 + hw0;
  const float* hb = hidden + (size_t)b * (C_DIM * 1024) + hw0;
  const int tid = threadIdx.x;

  for (int idx = tid; idx < C_DIM * 32; idx += 256) {
    int c = idx >> 5, q = idx & 31;
    xs[c][q] = hb[c * 1024 + q];     // coalesced over q
  }
  __syncthreads();

  if (tid < 128) {  // xsq partials, exact R1 c-ranges
    int q = tid & 31, part = tid >> 5, cb0 = part * 64;
    float s = 0.f;
    for (int c = 0; c < 64; ++c) { float v = xs[cb0 + c][q]; s = fmaf(v, v, s); }
    xsq_part[part][q] = s;
  }
  __syncthreads();
  if (tid < 32) {
    xsq[q0 + tid] = ((xsq_part[0][tid] + xsq_part[1][tid]) + xsq_part[2][tid]) +
                    xsq_part[3][tid];
    packed2[q0 + tid] = ~0ull;
  }

  {  // xt + xb row writes
    int q = tid >> 3, c0 = (tid & 7) * 32;
    float* xo = xt + (size_t)(q0 + q) * C_DIM + c0;
    unsigned short* bo = xb + (size_t)(q0 + q) * C_DIM + c0;
    for (int i = 0; i < 32; i += 4) {
      float4 v = {xs[c0 + i][q], xs[c0 + i + 1][q], xs[c0 + i + 2][q],
                  xs[c0 + i + 3][q]};
      *reinterpret_cast<float4*>(xo + i) = v;
      ushort4_t bv = {f2bf(v.x), f2bf(v.y), f2bf(v.z), f2bf(v.w)};
      *reinterpret_cast<ushort4_t*>(bo + i) = bv;
    }
  }
}

// ===========================================================================
// pre_e (R11-verified): coalesced staging; exact R1 esq chain; eb bf16.
// ===========================================================================
__global__ __launch_bounds__(256) void vq_pre_e(
    const float* __restrict__ cb, unsigned short* __restrict__ eb,
    float* __restrict__ esq) {
  __shared__ float es[64][257];
  const int k0 = blockIdx.x * 64;
  const int tid = threadIdx.x;

  for (int idx = tid; idx < 64 * 64; idx += 256) {
    int kk = idx >> 6, c4 = idx & 63;
    float4 v = reinterpret_cast<const float4*>(cb + (size_t)(k0 + kk) * C_DIM)[c4];
    es[kk][c4 * 4 + 0] = v.x; es[kk][c4 * 4 + 1] = v.y;
    es[kk][c4 * 4 + 2] = v.z; es[kk][c4 * 4 + 3] = v.w;
  }
  __syncthreads();

  if (tid < 64) {
    float s = 0.f;
    for (int c = 0; c < 256; ++c) { float v = es[tid][c]; s = fmaf(v, v, s); }
    esq[k0 + tid] = s;
  }

  {  // eb writes coalesced
    int r = tid >> 2, c0 = (tid & 3) * 64;
    unsigned short* bo = eb + (size_t)(k0 + r) * C_DIM + c0;
    for (int i = 0; i < 64; i += 4) {
      ushort4_t bv = {f2bf(es[r][c0 + i]), f2bf(es[r][c0 + i + 1]),
                      f2bf(es[r][c0 + i + 2]), f2bf(es[r][c0 + i + 3])};
      *reinterpret_cast<ushort4_t*>(bo + i) = bv;
    }
  }
}

// ===========================================================================
// Prefilter GEMM v4 — register-lean 128x128 tile for 4 waves/SIMD.
// 8 waves as 4(wr)x2(wc); wave tile 32x64 -> acc[2][4] = 32 AGPR (+~80 VGPR
// <= 128 total -> __launch_bounds__(512,4) = 4 waves/SIMD, 2 blocks/CU at
// 64KB LDS). Same R8-proven 3-bit XOR swizzle both-sides; same dbuf; same
// epilogue semantics (wc = one 64-code granule, g = nb*2 + wc).
// ===========================================================================
__global__ __launch_bounds__(512, 4) void vq_gemm(
    const unsigned short* __restrict__ xb, const unsigned short* __restrict__ eb,
    const float* __restrict__ xsq, const float* __restrict__ esq,
    float* __restrict__ mins_t) {
  __shared__ __align__(16) unsigned short As[2][BM * BK];  // 16KB x2
  __shared__ __align__(16) unsigned short Bs[2][BN * BK];  // 16KB x2

  const int tid = threadIdx.x;
  const int wid = tid >> 6;
  const int lane = tid & 63;

  int bidx = blockIdx.x;
  int xcd = bidx & 7;
  int idx = bidx >> 3;
  int nb = xcd * 16 + (idx >> 6);  // 0..127 k-tiles (16 per XCD slice)
  int qb = idx & 63;               // 0..63 q-tiles
  const int q0 = qb * BM;
  const int n0 = nb * BN;

  const int wr = wid >> 1, wc = wid & 1;  // 4x2 wave grid
  const int lrow = lane & 15;
  const int lkhi = lane >> 4;
  const int srow = lane >> 3;          // staging row within 8-row stripe
  const int sseg = (lane & 7) ^ srow;  // swizzled source segment (involution)

  auto stage = [&](int kt, int bf) {
#pragma unroll
    for (int i = 0; i < 2; ++i) {
      int r0 = (wid * 2 + i) * 8;  // 16 wave-issues cover 128 rows
      gl_lds16(xb + (size_t)(q0 + r0 + srow) * C_DIM + kt * BK + sseg * 8,
               (void*)((char*)&As[bf][0] + (size_t)r0 * BK * 2));
      gl_lds16(eb + (size_t)(n0 + r0 + srow) * C_DIM + kt * BK + sseg * 8,
               (void*)((char*)&Bs[bf][0] + (size_t)r0 * BK * 2));
    }
  };

  f32x4 acc[2][4];
#pragma unroll
  for (int i = 0; i < 2; ++i)
#pragma unroll
    for (int j = 0; j < 4; ++j) acc[i][j] = (f32x4){0.f, 0.f, 0.f, 0.f};

  stage(0, 0);
  asm volatile("s_waitcnt vmcnt(0)" ::: "memory");
  __syncthreads();

  const int r7 = lrow & 7;
  for (int kt = 0; kt < C_DIM / BK; ++kt) {
    int bf = kt & 1;
    if (kt + 1 < C_DIM / BK) stage(kt + 1, bf ^ 1);
#pragma unroll
    for (int kk = 0; kk < 2; ++kk) {
      const int segA = ((kk * 4 + lkhi) ^ r7) * 8;  // swizzled read (elems)
      short8 a[2], b[4];
#pragma unroll
      for (int mi = 0; mi < 2; ++mi)
        a[mi] = *(const short8*)((const char*)&As[bf][0] +
                 (size_t)((wr * 32 + mi * 16 + lrow) * BK + segA) * 2);
#pragma unroll
      for (int ni = 0; ni < 4; ++ni)
        b[ni] = *(const short8*)((const char*)&Bs[bf][0] +
                 (size_t)((wc * 64 + ni * 16 + lrow) * BK + segA) * 2);
#pragma unroll
      for (int mi = 0; mi < 2; ++mi)
#pragma unroll
        for (int ni = 0; ni < 4; ++ni)
          acc[mi][ni] = __builtin_amdgcn_mfma_f32_16x16x32_bf16(
              a[mi], b[ni], acc[mi][ni], 0, 0, 0);
    }
    asm volatile("s_waitcnt vmcnt(0)" ::: "memory");
    __syncthreads();
  }

  float eqv[4];
#pragma unroll
  for (int ni = 0; ni < 4; ++ni) eqv[ni] = esq[n0 + wc * 64 + ni * 16 + lrow];
  const int g = nb * 2 + wc;
#pragma unroll
  for (int mi = 0; mi < 2; ++mi) {
#pragma unroll
    for (int j = 0; j < 4; ++j) {
      int row = q0 + wr * 32 + mi * 16 + lkhi * 4 + j;
      float xq = xsq[row];
      u64 bst = ~0ull;
#pragma unroll
      for (int ni = 0; ni < 4; ++ni) {
        float d = (xq + eqv[ni]) - 2.0f * acc[mi][ni][j];
        int k = n0 + wc * 64 + ni * 16 + lrow;
        u64 p = ((u64)__float_as_uint(d) << 32) | (unsigned)k;
        if (p < bst) bst = p;
      }
#pragma unroll
      for (int m = 1; m <= 8; m <<= 1) {
        u64 o = __shfl_xor(bst, m);
        if (o < bst) bst = o;
      }
      if (lrow == 0)
        mins_t[(size_t)g * N_Q + row] = __uint_as_float((unsigned)(bst >> 32));
    }
  }
}

// ===========================================================================
// thr (R15-verified): 256 blocks x 32 queries, 8-way cooperative column-min.
// ===========================================================================
__global__ __launch_bounds__(256) void vq_thr(const float* __restrict__ mins_t,
                                              float* __restrict__ thr,
                                              int* __restrict__ gcnt,
                                              int* __restrict__ gcursor,
                                              int* __restrict__ meta) {
  __shared__ float pm[8][32];
  const int q0 = blockIdx.x * 32;
  const int tid = threadIdx.x;
  const int ql = tid & 31;
  const int part = tid >> 5;
  float m = 3.4e38f;
  for (int g = part * 32; g < part * 32 + 32; ++g)
    m = fminf(m, mins_t[(size_t)g * N_Q + q0 + ql]);
  pm[part][ql] = m;
  __syncthreads();
  if (tid < 32) {
    float mm = pm[0][tid];
#pragma unroll
    for (int p = 1; p < 8; ++p) mm = fminf(mm, pm[p][tid]);
    thr[q0 + tid] = mm + MARGIN;
  }
  if (blockIdx.x < 8 && tid < 32) {
    int g = blockIdx.x * 32 + tid;
    gcnt[g] = 0;
    gcursor[g] = 0;
  }
  if (blockIdx.x == 0 && tid < 4) meta[tid] = 0;
}

// ===========================================================================
// hist (R14-verified): block per granule, coalesced row scan, reduce.
// ===========================================================================
__global__ __launch_bounds__(256) void vq_hist(const float* __restrict__ mins_t,
                                               const float* __restrict__ thr,
                                               int* __restrict__ gcnt) {
  __shared__ int wsum[4];
  const int g = blockIdx.x;
  const int tid = threadIdx.x;
  const float* mrow = mins_t + (size_t)g * N_Q;
  int cnt = 0;
  for (int c = tid; c < N_Q; c += 256)
    if (mrow[c] <= thr[c]) ++cnt;
#pragma unroll
  for (int s = 1; s <= 32; s <<= 1) cnt += __shfl_xor(cnt, s);
  if ((tid & 63) == 0) wsum[tid >> 6] = cnt;
  __syncthreads();
  if (tid == 0) gcnt[g] = ((wsum[0] + wsum[1]) + wsum[2]) + wsum[3];
}

// ===========================================================================
// chunks (R13/R14-verified): 1 block; prefix sums -> goff + uniform <=64-pair
// chunk descriptors; overflow -> mode=1.
// ===========================================================================
__global__ __launch_bounds__(256) void vq_chunks(const int* __restrict__ gcnt,
                                                 int* __restrict__ goff,
                                                 unsigned* __restrict__ chunks,
                                                 int* __restrict__ meta) {
  __shared__ int cnt[NGRAN], off[NGRAN + 1], nch[NGRAN], choff[NGRAN + 1];
  const int tid = threadIdx.x;
  cnt[tid] = gcnt[tid];
  __syncthreads();
  if (tid == 0) {
    int s = 0;
    for (int g = 0; g < NGRAN; ++g) { off[g] = s; s += cnt[g]; }
    off[NGRAN] = s;
  }
  __syncthreads();
  nch[tid] = (cnt[tid] + 63) >> 6;
  __syncthreads();
  if (tid == 0) {
    int s = 0;
    for (int g = 0; g < NGRAN; ++g) { choff[g] = s; s += nch[g]; }
    choff[NGRAN] = s;
  }
  __syncthreads();
  const int P = off[NGRAN];
  const int C = choff[NGRAN];
  goff[tid] = off[tid];
  if (tid == 0) {
    goff[NGRAN] = P;
    meta[0] = P;
    meta[1] = (P > PCAP || C > CCAP) ? 2048 : C;
    meta[2] = (P > PCAP || C > CCAP) ? 1 : 0;
  }
  if (!(P > PCAP || C > CCAP)) {
    for (int c = 0; c < nch[tid]; ++c)
      chunks[choff[tid] + c] = ((unsigned)tid << 20) | (unsigned)(c * 64);
  }
}

// ===========================================================================
// scatter (R14-verified): block per (granule, slice); coalesced scan -> LDS
// compaction -> one segment-reserve atomic -> bulk copy.
// ===========================================================================
__global__ __launch_bounds__(256) void vq_scatter(
    const float* __restrict__ mins_t, const float* __restrict__ thr,
    const int* __restrict__ goff, int* __restrict__ gcursor,
    int* __restrict__ plist) {
  __shared__ int lbuf[RQB];
  __shared__ int lcnt;
  __shared__ int base;
  const int g = blockIdx.x;
  const int q0 = blockIdx.y * RQB;
  const int tid = threadIdx.x;
  if (tid == 0) lcnt = 0;
  __syncthreads();
  const float* mrow = mins_t + (size_t)g * N_Q + q0;
  for (int c = tid; c < RQB; c += 256) {
    if (mrow[c] <= thr[q0 + c]) {
      int pos = atomicAdd(&lcnt, 1);
      lbuf[pos] = q0 + c;
    }
  }
  __syncthreads();
  if (tid == 0) base = atomicAdd(&gcursor[g], lcnt);
  __syncthreads();
  const int b0 = goff[g] + base;
  for (int i = tid; i < lcnt; i += 256) {
    int idx = b0 + i;
    if (idx < PCAP) plist[idx] = lbuf[i];
  }
}

// ===========================================================================
// rescore v8 — QUARTER-GRANULE chunks (16 codes, cL 16.4KB -> ~7 blocks/CU).
// Lanes split 4 ways: qsel = l>>4 selects one of 4 list entries, cloc = l&15
// the code. Per wave: 4 ILP slots x 4 qsel = 16 entries per sweep; 4 waves
// cover a 64-entry chunk in one pass. EXACT R1 fmaf chain per lane; 16-lane
// shfl reduce; cloc==0 lanes atomicMin their query. Clamp-dup idempotent.
// ===========================================================================
__global__ __launch_bounds__(256) void vq_rescore_c(
    const float* __restrict__ xt, const float* __restrict__ cb,
    const float* __restrict__ xsq, const float* __restrict__ esq,
    const float* __restrict__ mins_t, const float* __restrict__ thr,
    const int* __restrict__ goff, const int* __restrict__ gcnt,
    const int* __restrict__ plist, const unsigned* __restrict__ chunks,
    const int* __restrict__ meta, u64* __restrict__ packed2) {
  __shared__ float cL[16][C_DIM + 1];  // 16.4KB (quarter granule)
  __shared__ int lbuf[RQB];            // fallback worklist (4KB)
  __shared__ int lcnt;
  const int tid = threadIdx.x;
  const int w = tid >> 6;
  const int l = tid & 63;
  const int cloc = l & 15;   // code within quarter
  const int qsel = l >> 4;   // which of 4 queries
  const int h = blockIdx.y;  // quarter-granule 0..3
  const int mode = meta[2];
  const int C = meta[1];

  auto stage_qtr = [&](int g) {
    const int row = tid >> 4;          // 0..15
    const int seg = tid & 15;          // 4 float4 each
    const float4* rp =
        (const float4*)(cb + (size_t)(g * GRAN + h * 16 + row) * C_DIM);
#pragma unroll
    for (int i = 0; i < 4; ++i) {
      int c4 = seg * 4 + i;
      float4 v = rp[c4];
      cL[row][c4 * 4 + 0] = v.x;
      cL[row][c4 * 4 + 1] = v.y;
      cL[row][c4 * 4 + 2] = v.z;
      cL[row][c4 * 4 + 3] = v.w;
    }
  };

  auto sweep = [&](int g, const int* list, int base, int n) {
    const int k = g * GRAN + h * 16 + cloc;
    const float eq = esq[k];
    const float* cr = &cL[cloc][0];
    for (int i0 = w * 16; i0 < n; i0 += 64) {
      int qi[4];
#pragma unroll
      for (int j = 0; j < 4; ++j) {
        int ii = i0 + 4 * j + qsel;
        qi[j] = list[base + (ii < n ? ii : n - 1)];  // clamp dup: idempotent
      }
      const float4* xp[4];
#pragma unroll
      for (int j = 0; j < 4; ++j)
        xp[j] = (const float4*)(xt + (size_t)qi[j] * C_DIM);
      float a[4];
#pragma unroll
      for (int j = 0; j < 4; ++j) a[j] = 0.f;
#pragma unroll 2
      for (int c4 = 0; c4 < 64; ++c4) {
        float e0 = cr[c4 * 4 + 0];
        float e1 = cr[c4 * 4 + 1];
        float e2 = cr[c4 * 4 + 2];
        float e3 = cr[c4 * 4 + 3];
#pragma unroll
        for (int j = 0; j < 4; ++j) {
          float4 v = xp[j][c4];  // 4 lines per instr (one per qsel group)
          float t = a[j];
          t = fmaf(v.x, e0, t);
          t = fmaf(v.y, e1, t);
          t = fmaf(v.z, e2, t);
          t = fmaf(v.w, e3, t);
          a[j] = t;
        }
      }
#pragma unroll
      for (int j = 0; j < 4; ++j) {
        float d = (xsq[qi[j]] + eq) - 2.0f * a[j];
        u64 p = ((u64)__float_as_uint(d) << 32) | (unsigned)k;
#pragma unroll
        for (int s = 1; s <= 8; s <<= 1) {  // 16-lane reduce (groups split)
          u64 o = __shfl_xor(p, s);
          if (o < p) p = o;
        }
        if (cloc == 0) atomicMin(&packed2[qi[j]], p);
      }
    }
  };

  if (mode == 0) {
    for (int ci = blockIdx.x; ci < C; ci += gridDim.x) {
      unsigned desc = chunks[ci];
      const int g = desc >> 20;
      const int s0 = desc & 0xFFFFF;
      const int n = min(64, gcnt[g] - s0);
      __syncthreads();
      stage_qtr(g);
      __syncthreads();
      sweep(g, plist, goff[g] + s0, n);
    }
    return;
  }

  // --------- fallback mode (P > PCAP): quarter-granule window scan -------
  if (blockIdx.x >= 2048) return;
  const int g = blockIdx.x >> 3;
  const int qbase = (blockIdx.x & 7) * RQB;
  if (tid == 0) lcnt = 0;
  __syncthreads();
  const float* mrow = mins_t + (size_t)g * N_Q + qbase;
  for (int c = tid; c < RQB; c += 256) {
    if (mrow[c] <= thr[qbase + c]) {
      int pos = atomicAdd(&lcnt, 1);
      lbuf[pos] = qbase + c;
    }
  }
  __syncthreads();
  const int n = lcnt;
  if (n == 0) return;
  stage_qtr(g);
  __syncthreads();
  sweep(g, lbuf, 0, n);
}

__global__ __launch_bounds__(256) void vq_out(const u64* __restrict__ packed2,
                                              int* __restrict__ out) {
  int n = blockIdx.x * 256 + threadIdx.x;
  if (n < N_Q) out[n] = (int)(unsigned)(packed2[n] & 0xffffffffull);
}

// ===========================================================================
// Fallback (R1, known-pass) if ws too small.
// ===========================================================================
#define TQ 64
#define TK 64
#define R1_NCH 8
#define R1_KCHUNK (N_K / R1_NCH)

__global__ __launch_bounds__(256) void r1_esq(const float* __restrict__ cb,
                                              float* __restrict__ esq) {
  int k = blockIdx.x * blockDim.x + threadIdx.x;
  if (k >= N_K) return;
  const float4* row = reinterpret_cast<const float4*>(cb + (size_t)k * C_DIM);
  float s = 0.f;
#pragma unroll 8
  for (int c4 = 0; c4 < C_DIM / 4; ++c4) {
    float4 v = row[c4];
    s = fmaf(v.x, v.x, s); s = fmaf(v.y, v.y, s);
    s = fmaf(v.z, v.z, s); s = fmaf(v.w, v.w, s);
  }
  esq[k] = s;
}

__global__ __launch_bounds__(256) void r1_main(
    const float* __restrict__ hidden, const float* __restrict__ cb,
    const float* __restrict__ esq, float* __restrict__ ws_d,
    int* __restrict__ ws_k) {
  __shared__ __align__(16) float xs[C_DIM][TQ + 4];
  __shared__ __align__(16) float es[TK][C_DIM + 4];
  __shared__ float xsq_part[4][TQ];
  __shared__ float xsq[TQ];
  __shared__ float red_d[16][TQ];
  __shared__ int red_k[16][TQ];
  const int tid = threadIdx.x;
  const int q0 = blockIdx.x * TQ;
  const int b = q0 >> 10;
  const int hw0 = q0 & 1023;
  const float* hb = hidden + (size_t)b * (C_DIM * 1024) + hw0;
  for (int idx = tid; idx < C_DIM * TQ; idx += 256) {
    int c = idx >> 6, q = idx & 63;
    xs[c][q] = hb[c * 1024 + q];
  }
  __syncthreads();
  {
    int q = tid & 63, part = tid >> 6, cbase = part * 64;
    float s = 0.f;
    for (int c = 0; c < 64; ++c) { float v = xs[cbase + c][q]; s = fmaf(v, v, s); }
    xsq_part[part][q] = s;
  }
  __syncthreads();
  if (tid < TQ)
    xsq[tid] = ((xsq_part[0][tid] + xsq_part[1][tid]) + xsq_part[2][tid]) + xsq_part[3][tid];
  __syncthreads();
  const int qt = tid & 15, kt = tid >> 4;
  float xsq_r[4];
#pragma unroll
  for (int i = 0; i < 4; ++i) xsq_r[i] = xsq[qt * 4 + i];
  float bd[4]; int bk[4];
#pragma unroll
  for (int i = 0; i < 4; ++i) { bd[i] = 3.4e38f; bk[i] = 0x7fffffff; }
  const int kbegin = blockIdx.y * R1_KCHUNK;
  for (int kt0 = kbegin; kt0 < kbegin + R1_KCHUNK; kt0 += TK) {
    __syncthreads();
    for (int idx = tid; idx < TK * (C_DIM / 4); idx += 256) {
      int kk = idx >> 6, c4 = idx & 63;
      float4 v = reinterpret_cast<const float4*>(cb + (size_t)(kt0 + kk) * C_DIM)[c4];
      es[kk][c4 * 4 + 0] = v.x; es[kk][c4 * 4 + 1] = v.y;
      es[kk][c4 * 4 + 2] = v.z; es[kk][c4 * 4 + 3] = v.w;
    }
    __syncthreads();
    float acc[4][4];
#pragma unroll
    for (int i = 0; i < 4; ++i)
#pragma unroll
      for (int j = 0; j < 4; ++j) acc[i][j] = 0.f;
    for (int c4 = 0; c4 < C_DIM; c4 += 4) {
      float4 xv0 = *reinterpret_cast<const float4*>(&xs[c4 + 0][qt * 4]);
      float4 xv1 = *reinterpret_cast<const float4*>(&xs[c4 + 1][qt * 4]);
      float4 xv2 = *reinterpret_cast<const float4*>(&xs[c4 + 2][qt * 4]);
      float4 xv3 = *reinterpret_cast<const float4*>(&xs[c4 + 3][qt * 4]);
      float xq0[4] = {xv0.x, xv0.y, xv0.z, xv0.w};
      float xq1[4] = {xv1.x, xv1.y, xv1.z, xv1.w};
      float xq2[4] = {xv2.x, xv2.y, xv2.z, xv2.w};
      float xq3[4] = {xv3.x, xv3.y, xv3.z, xv3.w};
      float4 ev[4];
#pragma unroll
      for (int j = 0; j < 4; ++j)
        ev[j] = *reinterpret_cast<const float4*>(&es[kt * 4 + j][c4]);
#pragma unroll
      for (int i = 0; i < 4; ++i) {
#pragma unroll
        for (int j = 0; j < 4; ++j) {
          float a = acc[i][j];
          a = fmaf(xq0[i], ev[j].x, a);
          a = fmaf(xq1[i], ev[j].y, a);
          a = fmaf(xq2[i], ev[j].z, a);
          a = fmaf(xq3[i], ev[j].w, a);
          acc[i][j] = a;
        }
      }
    }
#pragma unroll
    for (int j = 0; j < 4; ++j) {
      int k = kt0 + kt * 4 + j;
      float eq = esq[k];
#pragma unroll
      for (int i = 0; i < 4; ++i) {
        float t1 = xsq_r[i] + eq;
        float d = t1 - 2.0f * acc[i][j];
        if (d < bd[i]) { bd[i] = d; bk[i] = k; }
      }
    }
  }
#pragma unroll
  for (int i = 0; i < 4; ++i) {
    red_d[kt][qt * 4 + i] = bd[i];
    red_k[kt][qt * 4 + i] = bk[i];
  }
  __syncthreads();
  if (tid < TQ) {
    float d = red_d[0][tid]; int kb = red_k[0][tid];
    for (int t = 1; t < 16; ++t) {
      float dn = red_d[t][tid]; int kn = red_k[t][tid];
      if (dn < d || (dn == d && kn < kb)) { d = dn; kb = kn; }
    }
    int q = q0 + tid;
    ws_d[(size_t)q * R1_NCH + blockIdx.y] = d;
    ws_k[(size_t)q * R1_NCH + blockIdx.y] = kb;
  }
}

__global__ __launch_bounds__(256) void r1_final(
    const float* __restrict__ ws_d, const int* __restrict__ ws_k,
    int* __restrict__ out) {
  int n = blockIdx.x * blockDim.x + threadIdx.x;
  if (n >= N_Q) return;
  const float* dp = ws_d + (size_t)n * R1_NCH;
  const int* kp = ws_k + (size_t)n * R1_NCH;
  float d = dp[0]; int kb = kp[0];
#pragma unroll
  for (int j = 1; j < R1_NCH; ++j) {
    float dn = dp[j]; int kn = kp[j];
    if (dn < d || (dn == d && kn < kb)) { d = dn; kb = kn; }
  }
  out[n] = kb;
}

extern "C" void kernel_launch(void* const* d_in, const int* in_sizes, int n_in,
                              void* d_out, int out_size, void* d_ws,
                              size_t ws_size, hipStream_t stream) {
  const float* hidden = (const float*)d_in[0];
  const float* cb = (const float*)d_in[1];
  int* out = (int*)d_out;

  const size_t MB = 1024 * 1024;
  const size_t KB = 1024;
  const size_t NEED = 29 * MB;  // proven available (R3/R5-R15 passed)

  if (ws_size >= NEED) {
    char* w = (char*)d_ws;
    unsigned short* xb = (unsigned short*)(w);                 // 4MB
    unsigned short* eb = (unsigned short*)(w + 4 * MB);        // 8MB
    float* xt = (float*)(w + 12 * MB);                         // 8MB
    float* mins_t = (float*)(w + 20 * MB);                     // 8MB [g][q]
    char* s = w + 28 * MB;                                     // 1MB small pool
    float* xsq = (float*)(s);                                  // 32KB
    float* thr = (float*)(s + 32 * KB);                        // 32KB
    float* esq = (float*)(s + 64 * KB);                        // 64KB
    u64* packed2 = (u64*)(s + 128 * KB);                       // 64KB
    int* gcnt = (int*)(s + 192 * KB);                          // 1KB
    int* gcursor = (int*)(s + 193 * KB);                       // 1KB
    int* goff = (int*)(s + 194 * KB);                          // 2KB
    int* meta = (int*)(s + 196 * KB);                          // 1KB
    unsigned* chunks = (unsigned*)(s + 197 * KB);              // 16KB
    int* plist = (int*)(s + 213 * KB);                         // ~800KB (PCAP)

    vq_pre_x<<<dim3(256), dim3(256), 0, stream>>>(hidden, xt, xb, xsq, packed2);
    vq_pre_e<<<dim3(N_K / 64), dim3(256), 0, stream>>>(cb, eb, esq);
    vq_gemm<<<dim3((N_Q / BM) * (N_K / BN)), dim3(512), 0, stream>>>(
        xb, eb, xsq, esq, mins_t);
    vq_thr<<<dim3(N_Q / 32), dim3(256), 0, stream>>>(mins_t, thr, gcnt,
                                                     gcursor, meta);
    vq_hist<<<dim3(NGRAN), dim3(256), 0, stream>>>(mins_t, thr, gcnt);
    vq_chunks<<<dim3(1), dim3(256), 0, stream>>>(gcnt, goff, chunks, meta);
    vq_scatter<<<dim3(NGRAN, N_Q / RQB), dim3(256), 0, stream>>>(
        mins_t, thr, goff, gcursor, plist);
    vq_rescore_c<<<dim3(2048, 4), dim3(256), 0, stream>>>(
        xt, cb, xsq, esq, mins_t, thr, goff, gcnt, plist, chunks, meta,
        packed2);
    vq_out<<<dim3(N_Q / 256), dim3(256), 0, stream>>>(packed2, out);
  } else {
    float* esq_f = (float*)d_ws;
    float* ws_d = (float*)((char*)d_ws + 65536);
    int* ws_k = (int*)((char*)d_ws + 65536 + N_Q * R1_NCH * 4);
    r1_esq<<<dim3(N_K / 256), dim3(256), 0, stream>>>(cb, esq_f);
    r1_main<<<dim3(N_Q / TQ, R1_NCH), dim3(256), 0, stream>>>(hidden, cb, esq_f, ws_d, ws_k);
    r1_final<<<dim3(N_Q / 256), dim3(256), 0, stream>>>(ws_d, ws_k, out);
  }
}

// Round 17
// 244.613 us; speedup vs baseline: 2.2365x; 1.0563x over previous
//
#include <hip/hip_runtime.h>

#define N_Q 8192
#define N_K 16384
#define C_DIM 256
#define BM 128
#define BN 128
#define BK 64
#define NGRAN 256   // 64-code granules
#define GRAN 64
// Rigorous worst-case |d_approx - d_np| <= 1.9e-4; flagging needs 2x = 3.8e-4.
#define MARGIN 4.5e-4f
#define PCAP 200000      // pair-list capacity (overflow -> fallback mode)
#define CCAP 4096        // chunk descriptor capacity
#define RQB 1024         // fallback-mode / scatter slice size

typedef __attribute__((ext_vector_type(8))) short short8;
typedef __attribute__((ext_vector_type(4))) float f32x4;
typedef __attribute__((ext_vector_type(4))) unsigned short ushort4_t;
typedef unsigned long long u64;

__device__ inline unsigned short f2bf(float f) {  // RNE fp32->bf16 (finite)
  unsigned u = __float_as_uint(f);
  return (unsigned short)((u + 0x7fffu + ((u >> 16) & 1u)) >> 16);
}

__device__ inline void gl_lds16(const void* g, void* l) {
  __builtin_amdgcn_global_load_lds(
      (const __attribute__((address_space(1))) unsigned int*)g,
      (__attribute__((address_space(3))) unsigned int*)l, 16, 0, 0);
}

// ===========================================================================
// pre_x (R11-verified): LDS-tile transpose; exact R1 xsq order; init packed2.
// ===========================================================================
__global__ __launch_bounds__(256) void vq_pre_x(
    const float* __restrict__ hidden, float* __restrict__ xt,
    unsigned short* __restrict__ xb, float* __restrict__ xsq,
    u64* __restrict__ packed2) {
  __shared__ float xs[C_DIM][36];
  __shared__ float xsq_part[4][32];
  const int tile = blockIdx.x;       // 256 = 8 b x 32 hw-tiles
  const int b = tile >> 5;
  const int hw0 = (tile & 31) * 32;
  const int q0 = b * 1024 + hw0;
  const float* hb = hidden + (size_t)b * (C_DIM * 1024) + hw0;
  const int tid = threadIdx.x;

  for (int idx = tid; idx < C_DIM * 32; idx += 256) {
    int c = idx >> 5, q = idx & 31;
    xs[c][q] = hb[c * 1024 + q];     // coalesced over q
  }
  __syncthreads();

  if (tid < 128) {  // xsq partials, exact R1 c-ranges
    int q = tid & 31, part = tid >> 5, cb0 = part * 64;
    float s = 0.f;
    for (int c = 0; c < 64; ++c) { float v = xs[cb0 + c][q]; s = fmaf(v, v, s); }
    xsq_part[part][q] = s;
  }
  __syncthreads();
  if (tid < 32) {
    xsq[q0 + tid] = ((xsq_part[0][tid] + xsq_part[1][tid]) + xsq_part[2][tid]) +
                    xsq_part[3][tid];
    packed2[q0 + tid] = ~0ull;
  }

  {  // xt + xb row writes
    int q = tid >> 3, c0 = (tid & 7) * 32;
    float* xo = xt + (size_t)(q0 + q) * C_DIM + c0;
    unsigned short* bo = xb + (size_t)(q0 + q) * C_DIM + c0;
    for (int i = 0; i < 32; i += 4) {
      float4 v = {xs[c0 + i][q], xs[c0 + i + 1][q], xs[c0 + i + 2][q],
                  xs[c0 + i + 3][q]};
      *reinterpret_cast<float4*>(xo + i) = v;
      ushort4_t bv = {f2bf(v.x), f2bf(v.y), f2bf(v.z), f2bf(v.w)};
      *reinterpret_cast<ushort4_t*>(bo + i) = bv;
    }
  }
}

// ===========================================================================
// pre_e (R11-verified): coalesced staging; exact R1 esq chain; eb bf16.
// ===========================================================================
__global__ __launch_bounds__(256) void vq_pre_e(
    const float* __restrict__ cb, unsigned short* __restrict__ eb,
    float* __restrict__ esq) {
  __shared__ float es[64][257];
  const int k0 = blockIdx.x * 64;
  const int tid = threadIdx.x;

  for (int idx = tid; idx < 64 * 64; idx += 256) {
    int kk = idx >> 6, c4 = idx & 63;
    float4 v = reinterpret_cast<const float4*>(cb + (size_t)(k0 + kk) * C_DIM)[c4];
    es[kk][c4 * 4 + 0] = v.x; es[kk][c4 * 4 + 1] = v.y;
    es[kk][c4 * 4 + 2] = v.z; es[kk][c4 * 4 + 3] = v.w;
  }
  __syncthreads();

  if (tid < 64) {
    float s = 0.f;
    for (int c = 0; c < 256; ++c) { float v = es[tid][c]; s = fmaf(v, v, s); }
    esq[k0 + tid] = s;
  }

  {  // eb writes coalesced
    int r = tid >> 2, c0 = (tid & 3) * 64;
    unsigned short* bo = eb + (size_t)(k0 + r) * C_DIM + c0;
    for (int i = 0; i < 64; i += 4) {
      ushort4_t bv = {f2bf(es[r][c0 + i]), f2bf(es[r][c0 + i + 1]),
                      f2bf(es[r][c0 + i + 2]), f2bf(es[r][c0 + i + 3])};
      *reinterpret_cast<ushort4_t*>(bo + i) = bv;
    }
  }
}

// ===========================================================================
// Prefilter GEMM v5 — R16 register-lean core (VGPR 52, 4 waves/SIMD,
// conflicts=0) + R17 L2-locality swizzle: per XCD, blocks ordered
// (qc, nb16, qi): 16 consecutive blocks share one 64KB B-panel and walk a
// 1MB A-chunk that stays L2-resident across nb16 -> per-XCD HBM ~ 8MB.
// Mapping-only change; epilogue semantics identical.
// ===========================================================================
__global__ __launch_bounds__(512, 4) void vq_gemm(
    const unsigned short* __restrict__ xb, const unsigned short* __restrict__ eb,
    const float* __restrict__ xsq, const float* __restrict__ esq,
    float* __restrict__ mins_t) {
  __shared__ __align__(16) unsigned short As[2][BM * BK];  // 16KB x2
  __shared__ __align__(16) unsigned short Bs[2][BN * BK];  // 16KB x2

  const int tid = threadIdx.x;
  const int wid = tid >> 6;
  const int lane = tid & 63;

  int bidx = blockIdx.x;
  int xcd = bidx & 7;
  int idx = bidx >> 3;             // 0..1023 within XCD
  int qc = idx >> 8;               // 0..3  (16-qb chunk)
  int nb16 = (idx >> 4) & 15;      // 0..15 (B panel within XCD slice)
  int qi = idx & 15;               // 0..15 (qb within chunk)
  int qb = qc * 16 + qi;           // 0..63
  int nb = xcd * 16 + nb16;        // 0..127
  const int q0 = qb * BM;
  const int n0 = nb * BN;

  const int wr = wid >> 1, wc = wid & 1;  // 4x2 wave grid
  const int lrow = lane & 15;
  const int lkhi = lane >> 4;
  const int srow = lane >> 3;          // staging row within 8-row stripe
  const int sseg = (lane & 7) ^ srow;  // swizzled source segment (involution)

  auto stage = [&](int kt, int bf) {
#pragma unroll
    for (int i = 0; i < 2; ++i) {
      int r0 = (wid * 2 + i) * 8;  // 16 wave-issues cover 128 rows
      gl_lds16(xb + (size_t)(q0 + r0 + srow) * C_DIM + kt * BK + sseg * 8,
               (void*)((char*)&As[bf][0] + (size_t)r0 * BK * 2));
      gl_lds16(eb + (size_t)(n0 + r0 + srow) * C_DIM + kt * BK + sseg * 8,
               (void*)((char*)&Bs[bf][0] + (size_t)r0 * BK * 2));
    }
  };

  f32x4 acc[2][4];
#pragma unroll
  for (int i = 0; i < 2; ++i)
#pragma unroll
    for (int j = 0; j < 4; ++j) acc[i][j] = (f32x4){0.f, 0.f, 0.f, 0.f};

  stage(0, 0);
  asm volatile("s_waitcnt vmcnt(0)" ::: "memory");
  __syncthreads();

  const int r7 = lrow & 7;
  for (int kt = 0; kt < C_DIM / BK; ++kt) {
    int bf = kt & 1;
    if (kt + 1 < C_DIM / BK) stage(kt + 1, bf ^ 1);
#pragma unroll
    for (int kk = 0; kk < 2; ++kk) {
      const int segA = ((kk * 4 + lkhi) ^ r7) * 8;  // swizzled read (elems)
      short8 a[2], b[4];
#pragma unroll
      for (int mi = 0; mi < 2; ++mi)
        a[mi] = *(const short8*)((const char*)&As[bf][0] +
                 (size_t)((wr * 32 + mi * 16 + lrow) * BK + segA) * 2);
#pragma unroll
      for (int ni = 0; ni < 4; ++ni)
        b[ni] = *(const short8*)((const char*)&Bs[bf][0] +
                 (size_t)((wc * 64 + ni * 16 + lrow) * BK + segA) * 2);
#pragma unroll
      for (int mi = 0; mi < 2; ++mi)
#pragma unroll
        for (int ni = 0; ni < 4; ++ni)
          acc[mi][ni] = __builtin_amdgcn_mfma_f32_16x16x32_bf16(
              a[mi], b[ni], acc[mi][ni], 0, 0, 0);
    }
    asm volatile("s_waitcnt vmcnt(0)" ::: "memory");
    __syncthreads();
  }

  float eqv[4];
#pragma unroll
  for (int ni = 0; ni < 4; ++ni) eqv[ni] = esq[n0 + wc * 64 + ni * 16 + lrow];
  const int g = nb * 2 + wc;
#pragma unroll
  for (int mi = 0; mi < 2; ++mi) {
#pragma unroll
    for (int j = 0; j < 4; ++j) {
      int row = q0 + wr * 32 + mi * 16 + lkhi * 4 + j;
      float xq = xsq[row];
      u64 bst = ~0ull;
#pragma unroll
      for (int ni = 0; ni < 4; ++ni) {
        float d = (xq + eqv[ni]) - 2.0f * acc[mi][ni][j];
        int k = n0 + wc * 64 + ni * 16 + lrow;
        u64 p = ((u64)__float_as_uint(d) << 32) | (unsigned)k;
        if (p < bst) bst = p;
      }
#pragma unroll
      for (int m = 1; m <= 8; m <<= 1) {
        u64 o = __shfl_xor(bst, m);
        if (o < bst) bst = o;
      }
      if (lrow == 0)
        mins_t[(size_t)g * N_Q + row] = __uint_as_float((unsigned)(bst >> 32));
    }
  }
}

// ===========================================================================
// thr (R15-verified): 256 blocks x 32 queries, 8-way cooperative column-min.
// ===========================================================================
__global__ __launch_bounds__(256) void vq_thr(const float* __restrict__ mins_t,
                                              float* __restrict__ thr,
                                              int* __restrict__ gcnt,
                                              int* __restrict__ gcursor,
                                              int* __restrict__ meta) {
  __shared__ float pm[8][32];
  const int q0 = blockIdx.x * 32;
  const int tid = threadIdx.x;
  const int ql = tid & 31;
  const int part = tid >> 5;
  float m = 3.4e38f;
  for (int g = part * 32; g < part * 32 + 32; ++g)
    m = fminf(m, mins_t[(size_t)g * N_Q + q0 + ql]);
  pm[part][ql] = m;
  __syncthreads();
  if (tid < 32) {
    float mm = pm[0][tid];
#pragma unroll
    for (int p = 1; p < 8; ++p) mm = fminf(mm, pm[p][tid]);
    thr[q0 + tid] = mm + MARGIN;
  }
  if (blockIdx.x < 8 && tid < 32) {
    int g = blockIdx.x * 32 + tid;
    gcnt[g] = 0;
    gcursor[g] = 0;
  }
  if (blockIdx.x == 0 && tid < 4) meta[tid] = 0;
}

// ===========================================================================
// hist (R14-verified): block per granule, coalesced row scan, reduce.
// ===========================================================================
__global__ __launch_bounds__(256) void vq_hist(const float* __restrict__ mins_t,
                                               const float* __restrict__ thr,
                                               int* __restrict__ gcnt) {
  __shared__ int wsum[4];
  const int g = blockIdx.x;
  const int tid = threadIdx.x;
  const float* mrow = mins_t + (size_t)g * N_Q;
  int cnt = 0;
  for (int c = tid; c < N_Q; c += 256)
    if (mrow[c] <= thr[c]) ++cnt;
#pragma unroll
  for (int s = 1; s <= 32; s <<= 1) cnt += __shfl_xor(cnt, s);
  if ((tid & 63) == 0) wsum[tid >> 6] = cnt;
  __syncthreads();
  if (tid == 0) gcnt[g] = ((wsum[0] + wsum[1]) + wsum[2]) + wsum[3];
}

// ===========================================================================
// chunks (R13/R14-verified): 1 block; prefix sums -> goff + uniform <=64-pair
// chunk descriptors; overflow -> mode=1.
// ===========================================================================
__global__ __launch_bounds__(256) void vq_chunks(const int* __restrict__ gcnt,
                                                 int* __restrict__ goff,
                                                 unsigned* __restrict__ chunks,
                                                 int* __restrict__ meta) {
  __shared__ int cnt[NGRAN], off[NGRAN + 1], nch[NGRAN], choff[NGRAN + 1];
  const int tid = threadIdx.x;
  cnt[tid] = gcnt[tid];
  __syncthreads();
  if (tid == 0) {
    int s = 0;
    for (int g = 0; g < NGRAN; ++g) { off[g] = s; s += cnt[g]; }
    off[NGRAN] = s;
  }
  __syncthreads();
  nch[tid] = (cnt[tid] + 63) >> 6;
  __syncthreads();
  if (tid == 0) {
    int s = 0;
    for (int g = 0; g < NGRAN; ++g) { choff[g] = s; s += nch[g]; }
    choff[NGRAN] = s;
  }
  __syncthreads();
  const int P = off[NGRAN];
  const int C = choff[NGRAN];
  goff[tid] = off[tid];
  if (tid == 0) {
    goff[NGRAN] = P;
    meta[0] = P;
    meta[1] = (P > PCAP || C > CCAP) ? 2048 : C;
    meta[2] = (P > PCAP || C > CCAP) ? 1 : 0;
  }
  if (!(P > PCAP || C > CCAP)) {
    for (int c = 0; c < nch[tid]; ++c)
      chunks[choff[tid] + c] = ((unsigned)tid << 20) | (unsigned)(c * 64);
  }
}

// ===========================================================================
// scatter (R14-verified): block per (granule, slice); coalesced scan -> LDS
// compaction -> one segment-reserve atomic -> bulk copy.
// ===========================================================================
__global__ __launch_bounds__(256) void vq_scatter(
    const float* __restrict__ mins_t, const float* __restrict__ thr,
    const int* __restrict__ goff, int* __restrict__ gcursor,
    int* __restrict__ plist) {
  __shared__ int lbuf[RQB];
  __shared__ int lcnt;
  __shared__ int base;
  const int g = blockIdx.x;
  const int q0 = blockIdx.y * RQB;
  const int tid = threadIdx.x;
  if (tid == 0) lcnt = 0;
  __syncthreads();
  const float* mrow = mins_t + (size_t)g * N_Q + q0;
  for (int c = tid; c < RQB; c += 256) {
    if (mrow[c] <= thr[q0 + c]) {
      int pos = atomicAdd(&lcnt, 1);
      lbuf[pos] = q0 + c;
    }
  }
  __syncthreads();
  if (tid == 0) base = atomicAdd(&gcursor[g], lcnt);
  __syncthreads();
  const int b0 = goff[g] + base;
  for (int i = tid; i < lcnt; i += 256) {
    int idx = b0 + i;
    if (idx < PCAP) plist[idx] = lbuf[i];
  }
}

// ===========================================================================
// rescore v8 (R16-verified): QUARTER-GRANULE chunks; grid.x=4096 so each
// block handles exactly one chunk (better balance). Same exact chains.
// ===========================================================================
__global__ __launch_bounds__(256) void vq_rescore_c(
    const float* __restrict__ xt, const float* __restrict__ cb,
    const float* __restrict__ xsq, const float* __restrict__ esq,
    const float* __restrict__ mins_t, const float* __restrict__ thr,
    const int* __restrict__ goff, const int* __restrict__ gcnt,
    const int* __restrict__ plist, const unsigned* __restrict__ chunks,
    const int* __restrict__ meta, u64* __restrict__ packed2) {
  __shared__ float cL[16][C_DIM + 1];  // 16.4KB (quarter granule)
  __shared__ int lbuf[RQB];            // fallback worklist (4KB)
  __shared__ int lcnt;
  const int tid = threadIdx.x;
  const int w = tid >> 6;
  const int l = tid & 63;
  const int cloc = l & 15;   // code within quarter
  const int qsel = l >> 4;   // which of 4 queries
  const int h = blockIdx.y;  // quarter-granule 0..3
  const int mode = meta[2];
  const int C = meta[1];

  auto stage_qtr = [&](int g) {
    const int row = tid >> 4;          // 0..15
    const int seg = tid & 15;          // 4 float4 each
    const float4* rp =
        (const float4*)(cb + (size_t)(g * GRAN + h * 16 + row) * C_DIM);
#pragma unroll
    for (int i = 0; i < 4; ++i) {
      int c4 = seg * 4 + i;
      float4 v = rp[c4];
      cL[row][c4 * 4 + 0] = v.x;
      cL[row][c4 * 4 + 1] = v.y;
      cL[row][c4 * 4 + 2] = v.z;
      cL[row][c4 * 4 + 3] = v.w;
    }
  };

  auto sweep = [&](int g, const int* list, int base, int n) {
    const int k = g * GRAN + h * 16 + cloc;
    const float eq = esq[k];
    const float* cr = &cL[cloc][0];
    for (int i0 = w * 16; i0 < n; i0 += 64) {
      int qi[4];
#pragma unroll
      for (int j = 0; j < 4; ++j) {
        int ii = i0 + 4 * j + qsel;
        qi[j] = list[base + (ii < n ? ii : n - 1)];  // clamp dup: idempotent
      }
      const float4* xp[4];
#pragma unroll
      for (int j = 0; j < 4; ++j)
        xp[j] = (const float4*)(xt + (size_t)qi[j] * C_DIM);
      float a[4];
#pragma unroll
      for (int j = 0; j < 4; ++j) a[j] = 0.f;
#pragma unroll 2
      for (int c4 = 0; c4 < 64; ++c4) {
        float e0 = cr[c4 * 4 + 0];
        float e1 = cr[c4 * 4 + 1];
        float e2 = cr[c4 * 4 + 2];
        float e3 = cr[c4 * 4 + 3];
#pragma unroll
        for (int j = 0; j < 4; ++j) {
          float4 v = xp[j][c4];  // one line per qsel group
          float t = a[j];
          t = fmaf(v.x, e0, t);
          t = fmaf(v.y, e1, t);
          t = fmaf(v.z, e2, t);
          t = fmaf(v.w, e3, t);
          a[j] = t;
        }
      }
#pragma unroll
      for (int j = 0; j < 4; ++j) {
        float d = (xsq[qi[j]] + eq) - 2.0f * a[j];
        u64 p = ((u64)__float_as_uint(d) << 32) | (unsigned)k;
#pragma unroll
        for (int s = 1; s <= 8; s <<= 1) {  // 16-lane reduce (groups split)
          u64 o = __shfl_xor(p, s);
          if (o < p) p = o;
        }
        if (cloc == 0) atomicMin(&packed2[qi[j]], p);
      }
    }
  };

  if (mode == 0) {
    for (int ci = blockIdx.x; ci < C; ci += gridDim.x) {
      unsigned desc = chunks[ci];
      const int g = desc >> 20;
      const int s0 = desc & 0xFFFFF;
      const int n = min(64, gcnt[g] - s0);
      __syncthreads();
      stage_qtr(g);
      __syncthreads();
      sweep(g, plist, goff[g] + s0, n);
    }
    return;
  }

  // --------- fallback mode (P > PCAP): quarter-granule window scan -------
  if (blockIdx.x >= 2048) return;
  const int g = blockIdx.x >> 3;
  const int qbase = (blockIdx.x & 7) * RQB;
  if (tid == 0) lcnt = 0;
  __syncthreads();
  const float* mrow = mins_t + (size_t)g * N_Q + qbase;
  for (int c = tid; c < RQB; c += 256) {
    if (mrow[c] <= thr[qbase + c]) {
      int pos = atomicAdd(&lcnt, 1);
      lbuf[pos] = qbase + c;
    }
  }
  __syncthreads();
  const int n = lcnt;
  if (n == 0) return;
  stage_qtr(g);
  __syncthreads();
  sweep(g, lbuf, 0, n);
}

__global__ __launch_bounds__(256) void vq_out(const u64* __restrict__ packed2,
                                              int* __restrict__ out) {
  int n = blockIdx.x * 256 + threadIdx.x;
  if (n < N_Q) out[n] = (int)(unsigned)(packed2[n] & 0xffffffffull);
}

// ===========================================================================
// Fallback (R1, known-pass) if ws too small.
// ===========================================================================
#define TQ 64
#define TK 64
#define R1_NCH 8
#define R1_KCHUNK (N_K / R1_NCH)

__global__ __launch_bounds__(256) void r1_esq(const float* __restrict__ cb,
                                              float* __restrict__ esq) {
  int k = blockIdx.x * blockDim.x + threadIdx.x;
  if (k >= N_K) return;
  const float4* row = reinterpret_cast<const float4*>(cb + (size_t)k * C_DIM);
  float s = 0.f;
#pragma unroll 8
  for (int c4 = 0; c4 < C_DIM / 4; ++c4) {
    float4 v = row[c4];
    s = fmaf(v.x, v.x, s); s = fmaf(v.y, v.y, s);
    s = fmaf(v.z, v.z, s); s = fmaf(v.w, v.w, s);
  }
  esq[k] = s;
}

__global__ __launch_bounds__(256) void r1_main(
    const float* __restrict__ hidden, const float* __restrict__ cb,
    const float* __restrict__ esq, float* __restrict__ ws_d,
    int* __restrict__ ws_k) {
  __shared__ __align__(16) float xs[C_DIM][TQ + 4];
  __shared__ __align__(16) float es[TK][C_DIM + 4];
  __shared__ float xsq_part[4][TQ];
  __shared__ float xsq[TQ];
  __shared__ float red_d[16][TQ];
  __shared__ int red_k[16][TQ];
  const int tid = threadIdx.x;
  const int q0 = blockIdx.x * TQ;
  const int b = q0 >> 10;
  const int hw0 = q0 & 1023;
  const float* hb = hidden + (size_t)b * (C_DIM * 1024) + hw0;
  for (int idx = tid; idx < C_DIM * TQ; idx += 256) {
    int c = idx >> 6, q = idx & 63;
    xs[c][q] = hb[c * 1024 + q];
  }
  __syncthreads();
  {
    int q = tid & 63, part = tid >> 6, cbase = part * 64;
    float s = 0.f;
    for (int c = 0; c < 64; ++c) { float v = xs[cbase + c][q]; s = fmaf(v, v, s); }
    xsq_part[part][q] = s;
  }
  __syncthreads();
  if (tid < TQ)
    xsq[tid] = ((xsq_part[0][tid] + xsq_part[1][tid]) + xsq_part[2][tid]) + xsq_part[3][tid];
  __syncthreads();
  const int qt = tid & 15, kt = tid >> 4;
  float xsq_r[4];
#pragma unroll
  for (int i = 0; i < 4; ++i) xsq_r[i] = xsq[qt * 4 + i];
  float bd[4]; int bk[4];
#pragma unroll
  for (int i = 0; i < 4; ++i) { bd[i] = 3.4e38f; bk[i] = 0x7fffffff; }
  const int kbegin = blockIdx.y * R1_KCHUNK;
  for (int kt0 = kbegin; kt0 < kbegin + R1_KCHUNK; kt0 += TK) {
    __syncthreads();
    for (int idx = tid; idx < TK * (C_DIM / 4); idx += 256) {
      int kk = idx >> 6, c4 = idx & 63;
      float4 v = reinterpret_cast<const float4*>(cb + (size_t)(kt0 + kk) * C_DIM)[c4];
      es[kk][c4 * 4 + 0] = v.x; es[kk][c4 * 4 + 1] = v.y;
      es[kk][c4 * 4 + 2] = v.z; es[kk][c4 * 4 + 3] = v.w;
    }
    __syncthreads();
    float acc[4][4];
#pragma unroll
    for (int i = 0; i < 4; ++i)
#pragma unroll
      for (int j = 0; j < 4; ++j) acc[i][j] = 0.f;
    for (int c4 = 0; c4 < C_DIM; c4 += 4) {
      float4 xv0 = *reinterpret_cast<const float4*>(&xs[c4 + 0][qt * 4]);
      float4 xv1 = *reinterpret_cast<const float4*>(&xs[c4 + 1][qt * 4]);
      float4 xv2 = *reinterpret_cast<const float4*>(&xs[c4 + 2][qt * 4]);
      float4 xv3 = *reinterpret_cast<const float4*>(&xs[c4 + 3][qt * 4]);
      float xq0[4] = {xv0.x, xv0.y, xv0.z, xv0.w};
      float xq1[4] = {xv1.x, xv1.y, xv1.z, xv1.w};
      float xq2[4] = {xv2.x, xv2.y, xv2.z, xv2.w};
      float xq3[4] = {xv3.x, xv3.y, xv3.z, xv3.w};
      float4 ev[4];
#pragma unroll
      for (int j = 0; j < 4; ++j)
        ev[j] = *reinterpret_cast<const float4*>(&es[kt * 4 + j][c4]);
#pragma unroll
      for (int i = 0; i < 4; ++i) {
#pragma unroll
        for (int j = 0; j < 4; ++j) {
          float a = acc[i][j];
          a = fmaf(xq0[i], ev[j].x, a);
          a = fmaf(xq1[i], ev[j].y, a);
          a = fmaf(xq2[i], ev[j].z, a);
          a = fmaf(xq3[i], ev[j].w, a);
          acc[i][j] = a;
        }
      }
    }
#pragma unroll
    for (int j = 0; j < 4; ++j) {
      int k = kt0 + kt * 4 + j;
      float eq = esq[k];
#pragma unroll
      for (int i = 0; i < 4; ++i) {
        float t1 = xsq_r[i] + eq;
        float d = t1 - 2.0f * acc[i][j];
        if (d < bd[i]) { bd[i] = d; bk[i] = k; }
      }
    }
  }
#pragma unroll
  for (int i = 0; i < 4; ++i) {
    red_d[kt][qt * 4 + i] = bd[i];
    red_k[kt][qt * 4 + i] = bk[i];
  }
  __syncthreads();
  if (tid < TQ) {
    float d = red_d[0][tid]; int kb = red_k[0][tid];
    for (int t = 1; t < 16; ++t) {
      float dn = red_d[t][tid]; int kn = red_k[t][tid];
      if (dn < d || (dn == d && kn < kb)) { d = dn; kb = kn; }
    }
    int q = q0 + tid;
    ws_d[(size_t)q * R1_NCH + blockIdx.y] = d;
    ws_k[(size_t)q * R1_NCH + blockIdx.y] = kb;
  }
}

__global__ __launch_bounds__(256) void r1_final(
    const float* __restrict__ ws_d, const int* __restrict__ ws_k,
    int* __restrict__ out) {
  int n = blockIdx.x * blockDim.x + threadIdx.x;
  if (n >= N_Q) return;
  const float* dp = ws_d + (size_t)n * R1_NCH;
  const int* kp = ws_k + (size_t)n * R1_NCH;
  float d = dp[0]; int kb = kp[0];
#pragma unroll
  for (int j = 1; j < R1_NCH; ++j) {
    float dn = dp[j]; int kn = kp[j];
    if (dn < d || (dn == d && kn < kb)) { d = dn; kb = kn; }
  }
  out[n] = kb;
}

extern "C" void kernel_launch(void* const* d_in, const int* in_sizes, int n_in,
                              void* d_out, int out_size, void* d_ws,
                              size_t ws_size, hipStream_t stream) {
  const float* hidden = (const float*)d_in[0];
  const float* cb = (const float*)d_in[1];
  int* out = (int*)d_out;

  const size_t MB = 1024 * 1024;
  const size_t KB = 1024;
  const size_t NEED = 29 * MB;  // proven available (R3/R5-R16 passed)

  if (ws_size >= NEED) {
    char* w = (char*)d_ws;
    unsigned short* xb = (unsigned short*)(w);                 // 4MB
    unsigned short* eb = (unsigned short*)(w + 4 * MB);        // 8MB
    float* xt = (float*)(w + 12 * MB);                         // 8MB
    float* mins_t = (float*)(w + 20 * MB);                     // 8MB [g][q]
    char* s = w + 28 * MB;                                     // 1MB small pool
    float* xsq = (float*)(s);                                  // 32KB
    float* thr = (float*)(s + 32 * KB);                        // 32KB
    float* esq = (float*)(s + 64 * KB);                        // 64KB
    u64* packed2 = (u64*)(s + 128 * KB);                       // 64KB
    int* gcnt = (int*)(s + 192 * KB);                          // 1KB
    int* gcursor = (int*)(s + 193 * KB);                       // 1KB
    int* goff = (int*)(s + 194 * KB);                          // 2KB
    int* meta = (int*)(s + 196 * KB);                          // 1KB
    unsigned* chunks = (unsigned*)(s + 197 * KB);              // 16KB
    int* plist = (int*)(s + 213 * KB);                         // ~800KB (PCAP)

    vq_pre_x<<<dim3(256), dim3(256), 0, stream>>>(hidden, xt, xb, xsq, packed2);
    vq_pre_e<<<dim3(N_K / 64), dim3(256), 0, stream>>>(cb, eb, esq);
    vq_gemm<<<dim3((N_Q / BM) * (N_K / BN)), dim3(512), 0, stream>>>(
        xb, eb, xsq, esq, mins_t);
    vq_thr<<<dim3(N_Q / 32), dim3(256), 0, stream>>>(mins_t, thr, gcnt,
                                                     gcursor, meta);
    vq_hist<<<dim3(NGRAN), dim3(256), 0, stream>>>(mins_t, thr, gcnt);
    vq_chunks<<<dim3(1), dim3(256), 0, stream>>>(gcnt, goff, chunks, meta);
    vq_scatter<<<dim3(NGRAN, N_Q / RQB), dim3(256), 0, stream>>>(
        mins_t, thr, goff, gcursor, plist);
    vq_rescore_c<<<dim3(4096, 4), dim3(256), 0, stream>>>(
        xt, cb, xsq, esq, mins_t, thr, goff, gcnt, plist, chunks, meta,
        packed2);
    vq_out<<<dim3(N_Q / 256), dim3(256), 0, stream>>>(packed2, out);
  } else {
    float* esq_f = (float*)d_ws;
    float* ws_d = (float*)((char*)d_ws + 65536);
    int* ws_k = (int*)((char*)d_ws + 65536 + N_Q * R1_NCH * 4);
    r1_esq<<<dim3(N_K / 256), dim3(256), 0, stream>>>(cb, esq_f);
    r1_main<<<dim3(N_Q / TQ, R1_NCH), dim3(256), 0, stream>>>(hidden, cb, esq_f, ws_d, ws_k);
    r1_final<<<dim3(N_Q / 256), dim3(256), 0, stream>>>(ws_d, ws_k, out);
  }
}